// Round 2
// baseline (10146.011 us; speedup 1.0000x reference)
//
#include <hip/hip_runtime.h>

#define T_STEPS 512
#define BATCH   128
#define DIN     512
#define HDIM    512
#define THREEH  1536
#define NGROUP  4      // batch groups
#define NSLICE  32     // column slices per group
#define BC      32     // batch rows per group
#define HC      16     // h columns per WG
#define NC      48     // 3*HC gate columns per WG
#define THREADS 256
#define LDK     520    // padded K stride in halves (+8 breaks bank conflicts)
#define LDG     49     // padded accumulator stride
#define FLAG_STRIDE 4  // uints per flag slot (16B apart)

typedef _Float16 half8 __attribute__((ext_vector_type(8)));
typedef float    f32x4 __attribute__((ext_vector_type(4)));

// Detect whether resets buffer is bool bytes or int32.
// int32 data: every word is 0 or 1. bool bytes: ~14% of words have bytes in
// positions 1..3 -> word value > 1.
__global__ void sniff_kernel(const unsigned int* __restrict__ w,
                             unsigned int* __restrict__ dec) {
  unsigned int local = 0;
  for (int i = threadIdx.x; i < (T_STEPS * BATCH) / 4; i += THREADS) {
    if (w[i] > 1u) local = 1u;
  }
  if (local) atomicOr(dec, 1u);
}

__device__ __forceinline__ void run_gemm(const _Float16* __restrict__ sAa,
                                         const _Float16* __restrict__ sW,
                                         float* __restrict__ sAcc,
                                         int wid, int lane) {
  const int fr = lane & 15;
  const int kb = (lane >> 4) * 8;
  // 6 C-tiles (mi 0..1, ni 0..2) over 4 waves
  for (int tile = wid; tile < 6; tile += 4) {
    int mi = tile / 3, ni = tile - mi * 3;
    const _Float16* ap = sAa + (mi * 16 + fr) * LDK + kb;
    const _Float16* bp = sW  + (ni * 16 + fr) * LDK + kb;
    f32x4 acc = {0.f, 0.f, 0.f, 0.f};
#pragma unroll
    for (int kk = 0; kk < DIN / 32; ++kk)
      acc = __builtin_amdgcn_mfma_f32_16x16x32_f16(
          *(const half8*)(ap + kk * 32),
          *(const half8*)(bp + kk * 32), acc, 0, 0, 0);
    int crow = mi * 16 + (lane >> 4) * 4;
    int ccol = ni * 16 + fr;
#pragma unroll
    for (int j = 0; j < 4; ++j) sAcc[(crow + j) * LDG + ccol] = acc[j];
  }
}

__global__ __launch_bounds__(THREADS, 1)
void gru_kernel(const float* __restrict__ carry,
                const float* __restrict__ ins,
                const void*  __restrict__ resets_raw,
                const float* __restrict__ Wi,
                const float* __restrict__ Wh,
                const float* __restrict__ bh,
                float* __restrict__ out,
                unsigned int* __restrict__ flags,
                const unsigned int* __restrict__ dec)
{
  __shared__ alignas(16) _Float16 sWi[NC * LDK];   // Wi^T slice, fp16
  __shared__ alignas(16) _Float16 sWh[NC * LDK];   // Wh^T slice, fp16
  __shared__ alignas(16) _Float16 sA [BC * LDK];   // staged A (x_t, then h_{t-1})
  __shared__ float sGi[BC * LDG];
  __shared__ float sGh[BC * LDG];
  __shared__ float sBh[NC];
  __shared__ int   sRst[BC];

  const int tid  = threadIdx.x;
  const int bid  = blockIdx.x;
  const int g    = bid & (NGROUP - 1);   // batch group
  const int p    = bid >> 2;             // column slice
  const int row0 = g * BC;
  const int col0 = p * HC;

  float* carryOut = out;
  float* ys = out + BATCH * HDIM;

  const unsigned int isBool = *dec;
  const unsigned char* r8  = (const unsigned char*)resets_raw;
  const int*           r32 = (const int*)resets_raw;

  // Load weight slices once (columns: gate group x own 16 cols), store W^T.
  for (int idx = tid; idx < DIN * NC; idx += THREADS) {
    int k  = idx / NC;
    int ci = idx - k * NC;
    int gcol = (ci >> 4) * HDIM + col0 + (ci & 15);
    sWi[ci * LDK + k] = (_Float16)Wi[k * THREEH + gcol];
    sWh[ci * LDK + k] = (_Float16)Wh[k * THREEH + gcol];
  }
  if (tid < NC) {
    int gcol = (tid >> 4) * HDIM + col0 + (tid & 15);
    sBh[tid] = bh[gcol];
  }

  // Own h slice lives in registers: thread -> elements (b, cj), (b, cj+1)
  float hreg[2];
  {
    int idx = tid * 2;
    int b0 = idx >> 4, c0 = idx & 15;
    hreg[0] = carry[(size_t)(row0 + b0) * HDIM + col0 + c0];
    hreg[1] = carry[(size_t)(row0 + b0) * HDIM + col0 + c0 + 1];
  }

  const int wid  = tid >> 6;
  const int lane = tid & 63;

  __syncthreads();

  for (int t = 0; t < T_STEPS; ++t) {
    // resets for this step
    if (tid < BC) {
      int off = t * BATCH + row0 + tid;
      sRst[tid] = isBool ? (int)r8[off] : r32[off];
    }
    // stage x_t (recurrence-independent)
    {
      const float4* src = (const float4*)(ins + (size_t)(t * BATCH + row0) * DIN);
      for (int i = tid; i < BC * (DIN / 4); i += THREADS) {
        int r = i >> 7, c4 = i & 127;
        float4 v = src[(size_t)r * 128 + c4];
        _Float16* d = &sA[r * LDK + c4 * 4];
        d[0] = (_Float16)v.x; d[1] = (_Float16)v.y;
        d[2] = (_Float16)v.z; d[3] = (_Float16)v.w;
      }
    }
    __syncthreads();
    run_gemm(sA, sWi, sGi, wid, lane);     // gi = x @ Wi_slice
    __syncthreads();                       // sGi done; sA free

    // wait for all group slices of h_{t-1}
    if (t > 0) {
      if (tid < NSLICE) {
        const unsigned int* f = &flags[(g + NGROUP * tid) * FLAG_STRIDE];
        while (__hip_atomic_load(f, __ATOMIC_RELAXED, __HIP_MEMORY_SCOPE_AGENT)
               < (unsigned)t)
          __builtin_amdgcn_s_sleep(2);
      }
      __syncthreads();
      __builtin_amdgcn_fence(__ATOMIC_ACQUIRE, "agent");
    }
    // stage reset-masked h_{t-1}
    {
      const float4* src = (t == 0)
        ? (const float4*)(carry + (size_t)row0 * HDIM)
        : (const float4*)(ys + ((size_t)(t - 1) * BATCH + row0) * HDIM);
      for (int i = tid; i < BC * (HDIM / 4); i += THREADS) {
        int r = i >> 7, c4 = i & 127;
        float4 v = src[(size_t)r * 128 + c4];
        float m = sRst[r] ? 0.f : 1.f;
        _Float16* d = &sA[r * LDK + c4 * 4];
        d[0] = (_Float16)(v.x * m); d[1] = (_Float16)(v.y * m);
        d[2] = (_Float16)(v.z * m); d[3] = (_Float16)(v.w * m);
      }
    }
    __syncthreads();
    run_gemm(sA, sWh, sGh, wid, lane);     // gh = h @ Wh_slice
    __syncthreads();

    // gates + output (h_prev from registers, reset-masked)
#pragma unroll
    for (int e = 0; e < 2; ++e) {
      int idx = tid * 2 + e;
      int b = idx >> 4, cj = idx & 15;
      float gir = sGi[b * LDG + cj];
      float giz = sGi[b * LDG + 16 + cj];
      float gin = sGi[b * LDG + 32 + cj];
      float ghr = sGh[b * LDG + cj]      + sBh[cj];
      float ghz = sGh[b * LDG + 16 + cj] + sBh[16 + cj];
      float ghn = sGh[b * LDG + 32 + cj] + sBh[32 + cj];
      float r = 1.f / (1.f + __expf(-(gir + ghr)));
      float z = 1.f / (1.f + __expf(-(giz + ghz)));
      float n = tanhf(gin + r * ghn);
      float hp = sRst[b] ? 0.f : hreg[e];
      float nh = (1.f - z) * n + z * hp;
      hreg[e] = nh;
      ys[((size_t)t * BATCH + row0 + b) * HDIM + col0 + cj] = nh;
      if (t == T_STEPS - 1)
        carryOut[(size_t)(row0 + b) * HDIM + col0 + cj] = nh;
    }
    __builtin_amdgcn_fence(__ATOMIC_RELEASE, "agent");
    __syncthreads();
    if (tid == 0)
      __hip_atomic_store(&flags[bid * FLAG_STRIDE], (unsigned)(t + 1),
                         __ATOMIC_RELEASE, __HIP_MEMORY_SCOPE_AGENT);
  }
}

extern "C" void kernel_launch(void* const* d_in, const int* in_sizes, int n_in,
                              void* d_out, int out_size, void* d_ws, size_t ws_size,
                              hipStream_t stream) {
  const float* carry  = (const float*)d_in[0];
  const float* ins    = (const float*)d_in[1];
  const void*  resets = (const void*)d_in[2];
  const float* Wi     = (const float*)d_in[3];
  const float* Wh     = (const float*)d_in[4];
  const float* bh     = (const float*)d_in[5];
  float* out = (float*)d_out;

  unsigned int* flags = (unsigned int*)d_ws;                       // 2048 B
  unsigned int* dec   = (unsigned int*)((char*)d_ws + 2048);       // 4 B

  // zero flags + decision every launch (graph-capturable async memset)
  (void)hipMemsetAsync(d_ws, 0, 4096, stream);

  sniff_kernel<<<dim3(1), dim3(THREADS), 0, stream>>>(
      (const unsigned int*)resets, dec);

  void* args[] = { (void*)&carry, (void*)&ins, (void*)&resets, (void*)&Wi,
                   (void*)&Wh, (void*)&bh, (void*)&out, (void*)&flags,
                   (void*)&dec };
  (void)hipLaunchCooperativeKernel((const void*)gru_kernel,
                                   dim3(NGROUP * NSLICE), dim3(THREADS),
                                   args, 0, stream);
}

// Round 3
// 4318.674 us; speedup vs baseline: 2.3493x; 2.3493x over previous
//
#include <hip/hip_runtime.h>

#define T_STEPS 512
#define BATCH   128
#define DIN     512
#define HDIM    512
#define THREEH  1536
#define NGROUP  4      // batch groups
#define NSLICE  32     // column slices per group
#define BC      32     // batch rows per group
#define HC      16     // h columns per WG
#define NC      48     // 3*HC gate columns per WG
#define THREADS 256
#define LDK     520    // padded K stride in halves (+8 breaks bank conflicts)
#define LDG     49     // padded accumulator stride
#define FLAG_STRIDE 4  // uints per flag slot (16B apart)
#define EX_DWORDS (NSLICE * BATCH * HC / 2)   // 32768 dwords = 128KB per slot

typedef _Float16 half8 __attribute__((ext_vector_type(8)));
typedef float    f32x4 __attribute__((ext_vector_type(4)));
typedef unsigned int uint4v __attribute__((ext_vector_type(4)));

// Detect whether resets buffer is bool bytes or int32.
__global__ void sniff_kernel(const unsigned int* __restrict__ w,
                             unsigned int* __restrict__ dec) {
  unsigned int local = 0;
  for (int i = threadIdx.x; i < (T_STEPS * BATCH) / 4; i += THREADS) {
    if (w[i] > 1u) local = 1u;
  }
  if (local) atomicOr(dec, 1u);
}

__device__ __forceinline__ void run_gemm(const _Float16* __restrict__ sAa,
                                         const _Float16* __restrict__ sW,
                                         float* __restrict__ sAcc,
                                         int wid, int lane) {
  const int fr = lane & 15;
  const int kb = (lane >> 4) * 8;
  for (int tile = wid; tile < 6; tile += 4) {
    int mi = tile / 3, ni = tile - mi * 3;
    const _Float16* ap = sAa + (mi * 16 + fr) * LDK + kb;
    const _Float16* bp = sW  + (ni * 16 + fr) * LDK + kb;
    f32x4 acc = {0.f, 0.f, 0.f, 0.f};
#pragma unroll
    for (int kk = 0; kk < DIN / 32; ++kk)
      acc = __builtin_amdgcn_mfma_f32_16x16x32_f16(
          *(const half8*)(ap + kk * 32),
          *(const half8*)(bp + kk * 32), acc, 0, 0, 0);
    int crow = mi * 16 + (lane >> 4) * 4;
    int ccol = ni * 16 + fr;
#pragma unroll
    for (int j = 0; j < 4; ++j) sAcc[(crow + j) * LDG + ccol] = acc[j];
  }
}

__global__ __launch_bounds__(THREADS, 1)
void gru_kernel(const float* __restrict__ carry,
                const float* __restrict__ ins,
                const void*  __restrict__ resets_raw,
                const float* __restrict__ Wi,
                const float* __restrict__ Wh,
                const float* __restrict__ bh,
                float* __restrict__ out,
                unsigned int* __restrict__ flags,
                unsigned int* __restrict__ ex0,
                unsigned int* __restrict__ ex1,
                const unsigned int* __restrict__ dec)
{
  __shared__ alignas(16) _Float16 sWi[NC * LDK];
  __shared__ alignas(16) _Float16 sWh[NC * LDK];
  __shared__ alignas(16) _Float16 sA [BC * LDK];
  __shared__ float sGi[BC * LDG];
  __shared__ float sGh[BC * LDG];
  __shared__ float sBh[NC];
  __shared__ int   sRst[BC];

  const int tid  = threadIdx.x;
  const int bid  = blockIdx.x;
  const int g    = bid & (NGROUP - 1);   // batch group
  const int p    = bid >> 2;             // column slice
  const int row0 = g * BC;
  const int col0 = p * HC;

  float* carryOut = out;
  float* ys = out + BATCH * HDIM;

  const unsigned int isBool = *dec;
  const unsigned char* r8  = (const unsigned char*)resets_raw;
  const int*           r32 = (const int*)resets_raw;

  unsigned int* ex[2] = { ex0, ex1 };

  // Load weight slices once, store W^T in fp16.
  for (int idx = tid; idx < DIN * NC; idx += THREADS) {
    int k  = idx / NC;
    int ci = idx - k * NC;
    int gcol = (ci >> 4) * HDIM + col0 + (ci & 15);
    sWi[ci * LDK + k] = (_Float16)Wi[k * THREEH + gcol];
    sWh[ci * LDK + k] = (_Float16)Wh[k * THREEH + gcol];
  }
  if (tid < NC) {
    int gcol = (tid >> 4) * HDIM + col0 + (tid & 15);
    sBh[tid] = bh[gcol];
  }

  // Own h slice in registers: thread -> (b = tid>>3, cols c=(tid*2)&15, c+1)
  float hreg[2];
  {
    int idx = tid * 2;
    int b0 = idx >> 4, c0 = idx & 15;
    hreg[0] = carry[(size_t)(row0 + b0) * HDIM + col0 + c0];
    hreg[1] = carry[(size_t)(row0 + b0) * HDIM + col0 + c0 + 1];
  }

  const int wid  = tid >> 6;
  const int lane = tid & 63;

  __syncthreads();

  for (int t = 0; t < T_STEPS; ++t) {
    if (tid < BC) {
      int off = t * BATCH + row0 + tid;
      sRst[tid] = isBool ? (int)r8[off] : r32[off];
    }
    // stage x_t (recurrence-independent)
    {
      const float4* src = (const float4*)(ins + (size_t)(t * BATCH + row0) * DIN);
      for (int i = tid; i < BC * (DIN / 4); i += THREADS) {
        int r = i >> 7, c4 = i & 127;
        float4 v = src[(size_t)r * 128 + c4];
        _Float16* d = &sA[r * LDK + c4 * 4];
        d[0] = (_Float16)v.x; d[1] = (_Float16)v.y;
        d[2] = (_Float16)v.z; d[3] = (_Float16)v.w;
      }
    }
    __syncthreads();
    run_gemm(sA, sWi, sGi, wid, lane);     // gi = x @ Wi_slice
    __syncthreads();                       // sGi done; sA free

    if (t == 0) {
      // stage reset-masked h from carry (f32 -> fp16)
      const float4* src = (const float4*)(carry + (size_t)row0 * HDIM);
      for (int i = tid; i < BC * (HDIM / 4); i += THREADS) {
        int r = i >> 7, c4 = i & 127;
        float4 v = src[(size_t)r * 128 + c4];
        float m = sRst[r] ? 0.f : 1.f;
        _Float16* d = &sA[r * LDK + c4 * 4];
        d[0] = (_Float16)(v.x * m); d[1] = (_Float16)(v.y * m);
        d[2] = (_Float16)(v.z * m); d[3] = (_Float16)(v.w * m);
      }
    } else {
      // wait for all cohort slices of h_{t-1}
      if (tid < NSLICE) {
        const unsigned int* fp = flags + (size_t)(g + NGROUP * tid) * FLAG_STRIDE;
        unsigned int fv;
        for (;;) {
          asm volatile("global_load_dword %0, %1, off sc0 sc1\n\t"
                       "s_waitcnt vmcnt(0)"
                       : "=v"(fv) : "v"(fp) : "memory");
          if (fv >= (unsigned)t) break;
          __builtin_amdgcn_s_sleep(1);
        }
      }
      __syncthreads();
      // read h_{t-1} from exchange slot (coherent loads), mask, stage to LDS
      const unsigned int* exsrc = ex[(t - 1) & 1];
      uint4v vv[8];
#pragma unroll
      for (int j = 0; j < 8; ++j) {
        int i = tid + THREADS * j;
        int p_ = i >> 6, b_ = (i >> 1) & 31, hw = (i & 1) << 2; // dword sub-off
        const unsigned int* sp = exsrc + p_ * 1024 + (row0 + b_) * 8 + hw;
        asm volatile("global_load_dwordx4 %0, %1, off sc0 sc1"
                     : "=v"(vv[j]) : "v"(sp) : "memory");
      }
      asm volatile("s_waitcnt vmcnt(0)" ::: "memory");
      __builtin_amdgcn_sched_barrier(0);
#pragma unroll
      for (int j = 0; j < 8; ++j) {
        int i = tid + THREADS * j;
        int p_ = i >> 6, b_ = (i >> 1) & 31, hw = (i & 1) << 3; // half sub-off
        half8 hv = *reinterpret_cast<half8*>(&vv[j]);
        half8 z = {(_Float16)0, (_Float16)0, (_Float16)0, (_Float16)0,
                   (_Float16)0, (_Float16)0, (_Float16)0, (_Float16)0};
        hv = sRst[b_] ? z : hv;
        *(half8*)&sA[b_ * LDK + p_ * 16 + hw] = hv;
      }
    }
    __syncthreads();
    run_gemm(sA, sWh, sGh, wid, lane);     // gh = h @ Wh_slice
    __syncthreads();

    // gates + output (h_prev from registers, reset-masked)
#pragma unroll
    for (int e = 0; e < 2; ++e) {
      int idx = tid * 2 + e;
      int b = idx >> 4, cj = idx & 15;
      float gir = sGi[b * LDG + cj];
      float giz = sGi[b * LDG + 16 + cj];
      float gin = sGi[b * LDG + 32 + cj];
      float ghr = sGh[b * LDG + cj]      + sBh[cj];
      float ghz = sGh[b * LDG + 16 + cj] + sBh[16 + cj];
      float ghn = sGh[b * LDG + 32 + cj] + sBh[32 + cj];
      float r = 1.f / (1.f + __expf(-(gir + ghr)));
      float z = 1.f / (1.f + __expf(-(giz + ghz)));
      float n = tanhf(gin + r * ghn);
      float hp = sRst[b] ? 0.f : hreg[e];
      float nh = (1.f - z) * n + z * hp;
      hreg[e] = nh;
      ys[((size_t)t * BATCH + row0 + b) * HDIM + col0 + cj] = nh;
      if (t == T_STEPS - 1)
        carryOut[(size_t)(row0 + b) * HDIM + col0 + cj] = nh;
    }

    // publish h_t slice: write-through dword (2 fp16) per thread
    {
      union { _Float16 h[2]; unsigned int u; } pk;
      pk.h[0] = (_Float16)hreg[0];
      pk.h[1] = (_Float16)hreg[1];
      unsigned int* dst = ex[t & 1] + p * 1024 + (row0 + (tid >> 3)) * 8 + (tid & 7);
      asm volatile("global_store_dword %0, %1, off sc0 sc1"
                   :: "v"(dst), "v"(pk.u) : "memory");
    }
    asm volatile("s_waitcnt vmcnt(0)" ::: "memory");  // per-wave drain
    __syncthreads();                                  // all waves drained
    if (tid == 0) {
      unsigned int* fdst = flags + (size_t)bid * FLAG_STRIDE;
      unsigned int val = (unsigned)(t + 1);
      asm volatile("global_store_dword %0, %1, off sc0 sc1"
                   :: "v"(fdst), "v"(val) : "memory");
    }
  }
}

extern "C" void kernel_launch(void* const* d_in, const int* in_sizes, int n_in,
                              void* d_out, int out_size, void* d_ws, size_t ws_size,
                              hipStream_t stream) {
  const float* carry  = (const float*)d_in[0];
  const float* ins    = (const float*)d_in[1];
  const void*  resets = (const void*)d_in[2];
  const float* Wi     = (const float*)d_in[3];
  const float* Wh     = (const float*)d_in[4];
  const float* bh     = (const float*)d_in[5];
  float* out = (float*)d_out;

  unsigned int* flags = (unsigned int*)d_ws;                          // 2KB
  unsigned int* dec   = (unsigned int*)((char*)d_ws + 2048);          // 4B
  unsigned int* ex0   = (unsigned int*)((char*)d_ws + 4096);          // 128KB
  unsigned int* ex1   = ex0 + EX_DWORDS;                              // 128KB

  // zero flags + decision every launch (graph-capturable async memset)
  (void)hipMemsetAsync(d_ws, 0, 4096, stream);

  sniff_kernel<<<dim3(1), dim3(THREADS), 0, stream>>>(
      (const unsigned int*)resets, dec);

  void* args[] = { (void*)&carry, (void*)&ins, (void*)&resets, (void*)&Wi,
                   (void*)&Wh, (void*)&bh, (void*)&out, (void*)&flags,
                   (void*)&ex0, (void*)&ex1, (void*)&dec };
  (void)hipLaunchCooperativeKernel((const void*)gru_kernel,
                                   dim3(NGROUP * NSLICE), dim3(THREADS),
                                   args, 0, stream);
}

// Round 4
// 4288.728 us; speedup vs baseline: 2.3657x; 1.0070x over previous
//
#include <hip/hip_runtime.h>

#define T_STEPS 512
#define BATCH   128
#define DIN     512
#define HDIM    512
#define THREEH  1536
#define NGROUP  4      // batch groups
#define NSLICE  32     // column slices per group
#define BC      32     // batch rows per group
#define HC      16     // h columns per WG
#define NC      48     // 3*HC gate columns per WG
#define THREADS 256
#define LDK     520    // padded K stride in halves
#define LDG     49     // padded accumulator stride
#define CNT_STRIDE 16  // dwords between group counters (64B)
#define EX_DWORDS (NSLICE * BATCH * HC / 2)   // 32768 dwords = 128KB per slot

typedef _Float16 half8 __attribute__((ext_vector_type(8)));
typedef float    f32x4 __attribute__((ext_vector_type(4)));
typedef unsigned int uint4v __attribute__((ext_vector_type(4)));

// Detect whether resets buffer is bool bytes or int32.
__global__ void sniff_kernel(const unsigned int* __restrict__ w,
                             unsigned int* __restrict__ dec) {
  unsigned int local = 0;
  for (int i = threadIdx.x; i < (T_STEPS * BATCH) / 4; i += THREADS) {
    if (w[i] > 1u) local = 1u;
  }
  if (local) atomicOr(dec, 1u);
}

__device__ __forceinline__ void run_gemm(const _Float16* __restrict__ sAa,
                                         const _Float16* __restrict__ sW,
                                         float* __restrict__ sAcc,
                                         int wid, int lane) {
  const int fr = lane & 15;
  const int kb = (lane >> 4) * 8;
  for (int tile = wid; tile < 6; tile += 4) {
    int mi = tile / 3, ni = tile - mi * 3;
    const _Float16* ap = sAa + (mi * 16 + fr) * LDK + kb;
    const _Float16* bp = sW  + (ni * 16 + fr) * LDK + kb;
    f32x4 acc = {0.f, 0.f, 0.f, 0.f};
#pragma unroll
    for (int kk = 0; kk < DIN / 32; ++kk)
      acc = __builtin_amdgcn_mfma_f32_16x16x32_f16(
          *(const half8*)(ap + kk * 32),
          *(const half8*)(bp + kk * 32), acc, 0, 0, 0);
    int crow = mi * 16 + (lane >> 4) * 4;
    int ccol = ni * 16 + fr;
#pragma unroll
    for (int j = 0; j < 4; ++j) sAcc[(crow + j) * LDG + ccol] = acc[j];
  }
}

__global__ __launch_bounds__(THREADS, 1)
void gru_kernel(const float* __restrict__ carry,
                const float* __restrict__ ins,
                const void*  __restrict__ resets_raw,
                const float* __restrict__ Wi,
                const float* __restrict__ Wh,
                const float* __restrict__ bh,
                float* __restrict__ out,
                unsigned int* __restrict__ cnt,
                unsigned int* __restrict__ ex0,
                unsigned int* __restrict__ ex1,
                const unsigned int* __restrict__ dec)
{
  __shared__ alignas(16) _Float16 sWi[NC * LDK];
  __shared__ alignas(16) _Float16 sWh[NC * LDK];
  __shared__ alignas(16) _Float16 sA [BC * LDK];   // time-shared: h-tile / x-tile
  __shared__ float sGi[BC * LDG];
  __shared__ float sGh[BC * LDG];
  __shared__ float sBh[NC];
  __shared__ int   sRst[BC];

  const int tid  = threadIdx.x;
  const int bid  = blockIdx.x;
  const int g    = bid & (NGROUP - 1);   // batch group
  const int p    = bid >> 2;             // column slice
  const int row0 = g * BC;
  const int col0 = p * HC;

  float* carryOut = out;
  float* ys = out + BATCH * HDIM;

  const unsigned int isBool = *dec;
  const unsigned char* r8  = (const unsigned char*)resets_raw;
  const int*           r32 = (const int*)resets_raw;

  unsigned int* ex[2] = { ex0, ex1 };
  unsigned int* myCnt = cnt + g * CNT_STRIDE;

  // Load weight slices once, store W^T in fp16.
  for (int idx = tid; idx < DIN * NC; idx += THREADS) {
    int k  = idx / NC;
    int ci = idx - k * NC;
    int gcol = (ci >> 4) * HDIM + col0 + (ci & 15);
    sWi[ci * LDK + k] = (_Float16)Wi[k * THREEH + gcol];
    sWh[ci * LDK + k] = (_Float16)Wh[k * THREEH + gcol];
  }
  if (tid < NC) {
    int gcol = (tid >> 4) * HDIM + col0 + (tid & 15);
    sBh[tid] = bh[gcol];
  }

  // Own h slice in registers
  float hreg[2];
  {
    int idx = tid * 2;
    int b0 = idx >> 4, c0 = idx & 15;
    hreg[0] = carry[(size_t)(row0 + b0) * HDIM + col0 + c0];
    hreg[1] = carry[(size_t)(row0 + b0) * HDIM + col0 + c0 + 1];
  }

  const int wid  = tid >> 6;
  const int lane = tid & 63;

  auto stageRst = [&](int t) {
    if (tid < BC) {
      int off = t * BATCH + row0 + tid;
      sRst[tid] = isBool ? (int)r8[off] : r32[off];
    }
  };
  auto stageX = [&](int t) {
    const float4* src = (const float4*)(ins + (size_t)(t * BATCH + row0) * DIN);
    for (int i = tid; i < BC * (DIN / 4); i += THREADS) {
      int r = i >> 7, c4 = i & 127;
      float4 v = src[(size_t)r * 128 + c4];
      _Float16* d = &sA[r * LDK + c4 * 4];
      d[0] = (_Float16)v.x; d[1] = (_Float16)v.y;
      d[2] = (_Float16)v.z; d[3] = (_Float16)v.w;
    }
  };

  // ---- prologue: rst(0), x(0) -> gi(0), carry -> sA ----
  stageRst(0);
  stageX(0);
  __syncthreads();
  run_gemm(sA, sWi, sGi, wid, lane);
  __syncthreads();
  {
    const float4* src = (const float4*)(carry + (size_t)row0 * HDIM);
    for (int i = tid; i < BC * (HDIM / 4); i += THREADS) {
      int r = i >> 7, c4 = i & 127;
      float4 v = src[(size_t)r * 128 + c4];
      float m = sRst[r] ? 0.f : 1.f;
      _Float16* d = &sA[r * LDK + c4 * 4];
      d[0] = (_Float16)(v.x * m); d[1] = (_Float16)(v.y * m);
      d[2] = (_Float16)(v.z * m); d[3] = (_Float16)(v.w * m);
    }
  }
  __syncthreads();

  for (int t = 0; t < T_STEPS; ++t) {
    if (t > 0) {
      // A: poll group counter (single address, all lanes coalesce)
      {
        const unsigned int target = 32u * (unsigned)t;
        unsigned int fv;
        for (;;) {
          asm volatile("global_load_dword %0, %1, off sc0 sc1\n\t"
                       "s_waitcnt vmcnt(0)"
                       : "=v"(fv) : "v"(myCnt) : "memory");
          if (fv >= target) break;
          __builtin_amdgcn_s_sleep(1);
        }
      }
      // B: coherent read h_{t-1}, mask by rst(t), stage to sA
      {
        const unsigned int* exsrc = ex[(t - 1) & 1];
        uint4v vv[8];
#pragma unroll
        for (int j = 0; j < 8; ++j) {
          int i = tid + THREADS * j;
          int p_ = i >> 6, b_ = (i >> 1) & 31, hw = (i & 1) << 2;
          const unsigned int* sp = exsrc + p_ * 1024 + (row0 + b_) * 8 + hw;
          asm volatile("global_load_dwordx4 %0, %1, off sc0 sc1"
                       : "=v"(vv[j]) : "v"(sp) : "memory");
        }
        asm volatile("s_waitcnt vmcnt(0)" ::: "memory");
        __builtin_amdgcn_sched_barrier(0);
#pragma unroll
        for (int j = 0; j < 8; ++j) {
          int i = tid + THREADS * j;
          int p_ = i >> 6, b_ = (i >> 1) & 31, hw = (i & 1) << 3;
          half8 hv = *reinterpret_cast<half8*>(&vv[j]);
          half8 z = {(_Float16)0, (_Float16)0, (_Float16)0, (_Float16)0,
                     (_Float16)0, (_Float16)0, (_Float16)0, (_Float16)0};
          hv = sRst[b_] ? z : hv;
          *(half8*)&sA[b_ * LDK + p_ * 16 + hw] = hv;
        }
      }
      __syncthreads();   // C
    }

    run_gemm(sA, sWh, sGh, wid, lane);   // D: gh = h @ Wh_slice
    __syncthreads();                     // E

    // F: gates (sGi from previous gi compute), publish, ys
    {
#pragma unroll
      for (int e = 0; e < 2; ++e) {
        int idx = tid * 2 + e;
        int b = idx >> 4, cj = idx & 15;
        float gir = sGi[b * LDG + cj];
        float giz = sGi[b * LDG + 16 + cj];
        float gin = sGi[b * LDG + 32 + cj];
        float ghr = sGh[b * LDG + cj]      + sBh[cj];
        float ghz = sGh[b * LDG + 16 + cj] + sBh[16 + cj];
        float ghn = sGh[b * LDG + 32 + cj] + sBh[32 + cj];
        float r = 1.f / (1.f + __expf(-(gir + ghr)));
        float z = 1.f / (1.f + __expf(-(giz + ghz)));
        float n = tanhf(gin + r * ghn);
        float hp = sRst[b] ? 0.f : hreg[e];
        hreg[e] = (1.f - z) * n + z * hp;
      }
      // publish first (longest-latency store), then ys
      union { _Float16 h[2]; unsigned int u; } pk;
      pk.h[0] = (_Float16)hreg[0];
      pk.h[1] = (_Float16)hreg[1];
      unsigned int* dst = ex[t & 1] + p * 1024 + (row0 + (tid >> 3)) * 8 + (tid & 7);
      asm volatile("global_store_dword %0, %1, off sc0 sc1"
                   :: "v"(dst), "v"(pk.u) : "memory");
      int b0 = (tid * 2) >> 4, c0 = (tid * 2) & 15;
      float2 yv = make_float2(hreg[0], hreg[1]);
      *(float2*)&ys[((size_t)t * BATCH + row0 + b0) * HDIM + col0 + c0] = yv;
      if (t == T_STEPS - 1)
        *(float2*)&carryOut[(size_t)(row0 + b0) * HDIM + col0 + c0] = yv;
    }
    asm volatile("s_waitcnt vmcnt(0)" ::: "memory");  // G: per-wave drain
    __syncthreads();                                  // H: all waves drained
    if (tid == 0) atomicAdd(myCnt, 1u);               // release-count

    if (t < T_STEPS - 1) {
      // I: recurrence-independent work hides the handoff latency
      stageRst(t + 1);
      stageX(t + 1);
      __syncthreads();                   // J
      run_gemm(sA, sWi, sGi, wid, lane); // K: gi(t+1)
      __syncthreads();                   // L (sA free for next h-stage)
    }
  }
}

extern "C" void kernel_launch(void* const* d_in, const int* in_sizes, int n_in,
                              void* d_out, int out_size, void* d_ws, size_t ws_size,
                              hipStream_t stream) {
  const float* carry  = (const float*)d_in[0];
  const float* ins    = (const float*)d_in[1];
  const void*  resets = (const void*)d_in[2];
  const float* Wi     = (const float*)d_in[3];
  const float* Wh     = (const float*)d_in[4];
  const float* bh     = (const float*)d_in[5];
  float* out = (float*)d_out;

  unsigned int* cnt = (unsigned int*)d_ws;                          // 2KB
  unsigned int* dec = (unsigned int*)((char*)d_ws + 2048);          // 4B
  unsigned int* ex0 = (unsigned int*)((char*)d_ws + 4096);          // 128KB
  unsigned int* ex1 = ex0 + EX_DWORDS;                              // 128KB

  (void)hipMemsetAsync(d_ws, 0, 4096, stream);

  sniff_kernel<<<dim3(1), dim3(THREADS), 0, stream>>>(
      (const unsigned int*)resets, dec);

  void* args[] = { (void*)&carry, (void*)&ins, (void*)&resets, (void*)&Wi,
                   (void*)&Wh, (void*)&bh, (void*)&out, (void*)&cnt,
                   (void*)&ex0, (void*)&ex1, (void*)&dec };
  (void)hipLaunchCooperativeKernel((const void*)gru_kernel,
                                   dim3(NGROUP * NSLICE), dim3(THREADS),
                                   args, 0, stream);
}

// Round 6
// 3825.115 us; speedup vs baseline: 2.6525x; 1.1212x over previous
//
#include <hip/hip_runtime.h>

#define T_STEPS 512
#define BATCH   128
#define DIN     512
#define HDIM    512
#define THREEH  1536
#define THREADS 256
#define LDK     520    // padded K stride in halves
#define LDG     49
#define NGROUP  4
#define NSLICE  32
#define BC      32
#define HC      16
#define NC      48
#define CNT_STRIDE 16
#define FLAG_STRIDE 4
#define SPIN_MAX (1 << 22)   // bounded spin: wedge -> wrong answer, not a hang
#define EX_DWORDS (NSLICE * BATCH * HC / 2)   // 32768 dwords = 128KB per slot
// ws layout
#define DEC_OFF    2048
#define EX_OFF     4096      // 2 x 128KB
#define GI_OFF     (1u<<20)
#define GI_BYTES   201326592ULL  // T*B*3H fp16

typedef _Float16 half8 __attribute__((ext_vector_type(8)));
typedef _Float16 half4v __attribute__((ext_vector_type(4)));
typedef float    f32x4 __attribute__((ext_vector_type(4)));
typedef unsigned int uint4v __attribute__((ext_vector_type(4)));

__global__ void sniff_kernel(const unsigned int* __restrict__ w,
                             unsigned int* __restrict__ dec) {
  unsigned int local = 0;
  for (int i = threadIdx.x; i < (T_STEPS * BATCH) / 4; i += THREADS) {
    if (w[i] > 1u) local = 1u;
  }
  if (local) atomicOr(dec, 1u);
}

__device__ __forceinline__ void run_gemm(const _Float16* __restrict__ sAa,
                                         const _Float16* __restrict__ sW,
                                         float* __restrict__ sAcc,
                                         int wid, int lane) {
  const int fr = lane & 15;
  const int kb = (lane >> 4) * 8;
  for (int tile = wid; tile < 6; tile += 4) {
    int mi = tile / 3, ni = tile - mi * 3;
    const _Float16* ap = sAa + (mi * 16 + fr) * LDK + kb;
    const _Float16* bp = sW  + (ni * 16 + fr) * LDK + kb;
    f32x4 acc = {0.f, 0.f, 0.f, 0.f};
#pragma unroll
    for (int kk = 0; kk < DIN / 32; ++kk)
      acc = __builtin_amdgcn_mfma_f32_16x16x32_f16(
          *(const half8*)(ap + kk * 32),
          *(const half8*)(bp + kk * 32), acc, 0, 0, 0);
    int crow = mi * 16 + (lane >> 4) * 4;
    int ccol = ni * 16 + fr;
#pragma unroll
    for (int j = 0; j < 4; ++j) sAcc[(crow + j) * LDG + ccol] = acc[j];
  }
}

// ======================= v1 fallback (round-4, proven) =======================
__global__ __launch_bounds__(THREADS, 1)
void gru_kernel_v1(const float* __restrict__ carry,
                   const float* __restrict__ ins,
                   const void*  __restrict__ resets_raw,
                   const float* __restrict__ Wi,
                   const float* __restrict__ Wh,
                   const float* __restrict__ bh,
                   float* __restrict__ out,
                   unsigned int* __restrict__ cnt,
                   unsigned int* __restrict__ ex0,
                   unsigned int* __restrict__ ex1,
                   const unsigned int* __restrict__ dec)
{
  __shared__ alignas(16) _Float16 sWi[NC * LDK];
  __shared__ alignas(16) _Float16 sWh[NC * LDK];
  __shared__ alignas(16) _Float16 sA [BC * LDK];
  __shared__ float sGi[BC * LDG];
  __shared__ float sGh[BC * LDG];
  __shared__ float sBh[NC];
  __shared__ int   sRst[BC];

  const int tid  = threadIdx.x;
  const int bid  = blockIdx.x;
  const int g    = bid & (NGROUP - 1);
  const int p    = bid >> 2;
  const int row0 = g * BC;
  const int col0 = p * HC;

  float* carryOut = out;
  float* ys = out + BATCH * HDIM;

  const unsigned int isBool = *dec;
  const unsigned char* r8  = (const unsigned char*)resets_raw;
  const int*           r32 = (const int*)resets_raw;

  unsigned int* ex[2] = { ex0, ex1 };
  unsigned int* myCnt = cnt + g * CNT_STRIDE;

  for (int idx = tid; idx < DIN * NC; idx += THREADS) {
    int k  = idx / NC;
    int ci = idx - k * NC;
    int gcol = (ci >> 4) * HDIM + col0 + (ci & 15);
    sWi[ci * LDK + k] = (_Float16)Wi[k * THREEH + gcol];
    sWh[ci * LDK + k] = (_Float16)Wh[k * THREEH + gcol];
  }
  if (tid < NC) {
    int gcol = (tid >> 4) * HDIM + col0 + (tid & 15);
    sBh[tid] = bh[gcol];
  }

  float hreg[2];
  {
    int idx = tid * 2;
    int b0 = idx >> 4, c0 = idx & 15;
    hreg[0] = carry[(size_t)(row0 + b0) * HDIM + col0 + c0];
    hreg[1] = carry[(size_t)(row0 + b0) * HDIM + col0 + c0 + 1];
  }

  const int wid  = tid >> 6;
  const int lane = tid & 63;

  auto stageRst = [&](int t) {
    if (tid < BC) {
      int off = t * BATCH + row0 + tid;
      sRst[tid] = isBool ? (int)r8[off] : r32[off];
    }
  };
  auto stageX = [&](int t) {
    const float4* src = (const float4*)(ins + (size_t)(t * BATCH + row0) * DIN);
    for (int i = tid; i < BC * (DIN / 4); i += THREADS) {
      int r = i >> 7, c4 = i & 127;
      float4 v = src[(size_t)r * 128 + c4];
      half4v hv = {(_Float16)v.x, (_Float16)v.y, (_Float16)v.z, (_Float16)v.w};
      *(half4v*)&sA[r * LDK + c4 * 4] = hv;
    }
  };

  stageRst(0);
  stageX(0);
  __syncthreads();
  run_gemm(sA, sWi, sGi, wid, lane);
  __syncthreads();
  {
    const float4* src = (const float4*)(carry + (size_t)row0 * HDIM);
    for (int i = tid; i < BC * (HDIM / 4); i += THREADS) {
      int r = i >> 7, c4 = i & 127;
      float4 v = src[(size_t)r * 128 + c4];
      float m = sRst[r] ? 0.f : 1.f;
      half4v hv = {(_Float16)(v.x*m), (_Float16)(v.y*m),
                   (_Float16)(v.z*m), (_Float16)(v.w*m)};
      *(half4v*)&sA[r * LDK + c4 * 4] = hv;
    }
  }
  __syncthreads();

  for (int t = 0; t < T_STEPS; ++t) {
    if (t > 0) {
      {
        const unsigned int target = 32u * (unsigned)t;
        unsigned int fv;
        for (int it = 0; it < SPIN_MAX; ++it) {
          asm volatile("global_load_dword %0, %1, off sc0 sc1\n\t"
                       "s_waitcnt vmcnt(0)"
                       : "=v"(fv) : "v"(myCnt) : "memory");
          if (fv >= target) break;
          __builtin_amdgcn_s_sleep(1);
        }
      }
      {
        const unsigned int* exsrc = ex[(t - 1) & 1];
        uint4v vv[8];
#pragma unroll
        for (int j = 0; j < 8; ++j) {
          int i = tid + THREADS * j;
          int p_ = i >> 6, b_ = (i >> 1) & 31, hw = (i & 1) << 2;
          const unsigned int* sp = exsrc + p_ * 1024 + (row0 + b_) * 8 + hw;
          asm volatile("global_load_dwordx4 %0, %1, off sc0 sc1"
                       : "=&v"(vv[j]) : "v"(sp) : "memory");
        }
        asm volatile("s_waitcnt vmcnt(0)" ::: "memory");
        __builtin_amdgcn_sched_barrier(0);
#pragma unroll
        for (int j = 0; j < 8; ++j) {
          int i = tid + THREADS * j;
          int p_ = i >> 6, b_ = (i >> 1) & 31, hw = (i & 1) << 3;
          half8 hv = *reinterpret_cast<half8*>(&vv[j]);
          half8 z = {(_Float16)0, (_Float16)0, (_Float16)0, (_Float16)0,
                     (_Float16)0, (_Float16)0, (_Float16)0, (_Float16)0};
          hv = sRst[b_] ? z : hv;
          *(half8*)&sA[b_ * LDK + p_ * 16 + hw] = hv;
        }
      }
      __syncthreads();
    }

    run_gemm(sA, sWh, sGh, wid, lane);
    __syncthreads();

    {
#pragma unroll
      for (int e = 0; e < 2; ++e) {
        int idx = tid * 2 + e;
        int b = idx >> 4, cj = idx & 15;
        float gir = sGi[b * LDG + cj];
        float giz = sGi[b * LDG + 16 + cj];
        float gin = sGi[b * LDG + 32 + cj];
        float ghr = sGh[b * LDG + cj]      + sBh[cj];
        float ghz = sGh[b * LDG + 16 + cj] + sBh[16 + cj];
        float ghn = sGh[b * LDG + 32 + cj] + sBh[32 + cj];
        float r = 1.f / (1.f + __expf(-(gir + ghr)));
        float z = 1.f / (1.f + __expf(-(giz + ghz)));
        float n = tanhf(gin + r * ghn);
        float hp = sRst[b] ? 0.f : hreg[e];
        hreg[e] = (1.f - z) * n + z * hp;
      }
      union { _Float16 h[2]; unsigned int u; } pk;
      pk.h[0] = (_Float16)hreg[0];
      pk.h[1] = (_Float16)hreg[1];
      unsigned int* dst = ex[t & 1] + p * 1024 + (row0 + (tid >> 3)) * 8 + (tid & 7);
      asm volatile("global_store_dword %0, %1, off sc0 sc1"
                   :: "v"(dst), "v"(pk.u) : "memory");
      int b0 = (tid * 2) >> 4, c0 = (tid * 2) & 15;
      float2 yv = make_float2(hreg[0], hreg[1]);
      *(float2*)&ys[((size_t)t * BATCH + row0 + b0) * HDIM + col0 + c0] = yv;
      if (t == T_STEPS - 1)
        *(float2*)&carryOut[(size_t)(row0 + b0) * HDIM + col0 + c0] = yv;
    }
    asm volatile("s_waitcnt vmcnt(0)" ::: "memory");
    __syncthreads();
    if (tid == 0) atomicAdd(myCnt, 1u);

    if (t < T_STEPS - 1) {
      stageRst(t + 1);
      stageX(t + 1);
      __syncthreads();
      run_gemm(sA, sWi, sGi, wid, lane);
      __syncthreads();
    }
  }
}

// ============ gi prepass: gis[t][gamma][b][h] fp16 (plain GEMM) ============
__global__ __launch_bounds__(256, 1)
void gi_prepass(const float* __restrict__ ins,
                const float* __restrict__ Wi,
                _Float16* __restrict__ gis)
{
  __shared__ alignas(16) _Float16 sWiT[48 * LDK];
  __shared__ alignas(16) _Float16 sX[32 * LDK];

  const int tid = threadIdx.x;
  const int bid = blockIdx.x;
  const int n   = bid >> 4;    // 32 col-slices (16 h-cols each)
  const int mg  = bid & 15;    // 16 M-groups of 4096 rows
  const int wid = tid >> 6;
  const int lane = tid & 63;
  const int fr = lane & 15;
  const int kb = (lane >> 4) * 8;

  for (int idx = tid; idx < 48 * DIN; idx += 256) {
    int ci = idx % 48, k = idx / 48;
    int gcol = (ci >> 4) * HDIM + n * 16 + (ci & 15);
    sWiT[ci * LDK + k] = (_Float16)Wi[(size_t)k * THREEH + gcol];
  }
  __syncthreads();

  for (int ch = 0; ch < 128; ++ch) {
    const int m0 = mg * 4096 + ch * 32;
    const float4* src = (const float4*)(ins + (size_t)m0 * DIN);
    for (int i = tid; i < 32 * 128; i += 256) {
      int r = i >> 7, c4 = i & 127;
      float4 v = src[(size_t)r * 128 + c4];
      half4v hv = {(_Float16)v.x, (_Float16)v.y, (_Float16)v.z, (_Float16)v.w};
      *(half4v*)&sX[r * LDK + c4 * 4] = hv;
    }
    __syncthreads();

    const int tt = m0 >> 7;          // 32-row chunk never crosses a t boundary
    const int bb0 = m0 & 127;
    for (int tile = wid; tile < 6; tile += 4) {
      int mi = tile / 3, ni = tile - mi * 3;
      const _Float16* ap = sX   + (mi * 16 + fr) * LDK + kb;
      const _Float16* bp = sWiT + (ni * 16 + fr) * LDK + kb;
      f32x4 acc = {0.f, 0.f, 0.f, 0.f};
#pragma unroll
      for (int kk = 0; kk < DIN / 32; ++kk)
        acc = __builtin_amdgcn_mfma_f32_16x16x32_f16(
            *(const half8*)(ap + kk * 32),
            *(const half8*)(bp + kk * 32), acc, 0, 0, 0);
      int gr = mi * 16 + ((lane >> 4) << 2);
      int col = n * 16 + fr;
      size_t base = ((size_t)(tt * 3 + ni) * BATCH) * HDIM + col;
#pragma unroll
      for (int j = 0; j < 4; ++j)
        gis[base + (size_t)(bb0 + gr + j) * HDIM] = (_Float16)acc[j];
    }
    __syncthreads();
  }
}

// ============ v3: slim recurrent loop (gi from prepass buffer) ============
__global__ __launch_bounds__(THREADS, 1)
void gru_kernel_v3(const float* __restrict__ carry,
                   const void*  __restrict__ resets_raw,
                   const float* __restrict__ Wh,
                   const float* __restrict__ bh,
                   float* __restrict__ out,
                   unsigned int* __restrict__ flags,
                   unsigned int* __restrict__ ex0,
                   unsigned int* __restrict__ ex1,
                   const _Float16* __restrict__ gis,
                   const unsigned int* __restrict__ dec)
{
  __shared__ alignas(16) _Float16 sWh[NC * LDK];   // ~50KB
  __shared__ alignas(16) _Float16 sA [BC * LDK];   // ~33KB
  __shared__ float sGh[BC * LDG];
  __shared__ float sBh[NC];
  __shared__ int   sRst[BC];

  const int tid  = threadIdx.x;
  const int bid  = blockIdx.x;
  const int g    = bid & (NGROUP - 1);
  const int p    = bid >> 2;
  const int row0 = g * BC;
  const int col0 = p * HC;

  float* carryOut = out;
  float* ys = out + BATCH * HDIM;

  const unsigned int isBool = *dec;
  const unsigned char* r8  = (const unsigned char*)resets_raw;
  const int*           r32 = (const int*)resets_raw;

  unsigned int* ex[2] = { ex0, ex1 };

  for (int idx = tid; idx < DIN * NC; idx += THREADS) {
    int k  = idx / NC;
    int ci = idx - k * NC;
    int gcol = (ci >> 4) * HDIM + col0 + (ci & 15);
    sWh[ci * LDK + k] = (_Float16)Wh[k * THREEH + gcol];
  }
  if (tid < NC) {
    int gcol = (tid >> 4) * HDIM + col0 + (tid & 15);
    sBh[tid] = bh[gcol];
  }

  float hreg[2];
  {
    int idx = tid * 2;
    int b0 = idx >> 4, c0 = idx & 15;
    hreg[0] = carry[(size_t)(row0 + b0) * HDIM + col0 + c0];
    hreg[1] = carry[(size_t)(row0 + b0) * HDIM + col0 + c0 + 1];
  }

  const int wid  = tid >> 6;
  const int lane = tid & 63;
  const int gb   = tid >> 3;          // gates: batch row 0..31
  const int gcd  = tid & 7;           // gates: dword (2 cols) within 16

  // prologue: rst(0), stage masked carry into sA
  if (tid < BC) {
    int off = row0 + tid;
    sRst[tid] = isBool ? (int)r8[off] : r32[off];
  }
  __syncthreads();
  {
    const float4* src = (const float4*)(carry + (size_t)row0 * HDIM);
    for (int i = tid; i < BC * (HDIM / 4); i += THREADS) {
      int r = i >> 7, c4 = i & 127;
      float4 v = src[(size_t)r * 128 + c4];
      float m = sRst[r] ? 0.f : 1.f;
      half4v hv = {(_Float16)(v.x*m), (_Float16)(v.y*m),
                   (_Float16)(v.z*m), (_Float16)(v.w*m)};
      *(half4v*)&sA[r * LDK + c4 * 4] = hv;
    }
  }

  for (int t = 0; t < T_STEPS; ++t) {
    // prefetch gi (plain cached loads; independent of recurrence)
    unsigned int giu0, giu1, giu2;
    {
      const unsigned int* gp = (const unsigned int*)gis
        + ((((size_t)(t * 3) * BATCH + row0 + gb) * HDIM + col0) >> 1) + gcd;
      const size_t gstride = (size_t)BATCH * HDIM / 2;  // gamma stride in dwords
      giu0 = gp[0];
      giu1 = gp[gstride];
      giu2 = gp[2 * gstride];
    }
    // rst(t) upgrade (t=0 done in prologue)
    if (t > 0 && tid < BC) {
      int off = t * BATCH + row0 + tid;
      sRst[tid] = isBool ? (int)r8[off] : r32[off];
    }
    // wait for cohort h_{t-1} (parallel per-slice flags, bounded spin)
    if (t > 0 && tid < NSLICE) {
      const unsigned int* fp = flags + (size_t)(g + NGROUP * tid) * FLAG_STRIDE;
      unsigned int fv;
      for (int it = 0; it < SPIN_MAX; ++it) {
        asm volatile("global_load_dword %0, %1, off sc0 sc1\n\t"
                     "s_waitcnt vmcnt(0)"
                     : "=v"(fv) : "v"(fp) : "memory");
        if (fv >= (unsigned)t) break;
        __builtin_amdgcn_s_sleep(1);
      }
    }
    __syncthreads();   // A: sRst visible; flags passed; sA(t=0) staged

    if (t > 0) {
      const unsigned int* exsrc = ex[(t - 1) & 1];
      uint4v vv[8];
#pragma unroll
      for (int j = 0; j < 8; ++j) {
        int i = tid + THREADS * j;
        int p_ = i >> 6, b_ = (i >> 1) & 31, hw = (i & 1) << 2;
        const unsigned int* sp = exsrc + p_ * 1024 + (row0 + b_) * 8 + hw;
        asm volatile("global_load_dwordx4 %0, %1, off sc0 sc1"
                     : "=&v"(vv[j]) : "v"(sp) : "memory");
      }
      asm volatile("s_waitcnt vmcnt(0)" ::: "memory");
      __builtin_amdgcn_sched_barrier(0);
#pragma unroll
      for (int j = 0; j < 8; ++j) {
        int i = tid + THREADS * j;
        int p_ = i >> 6, b_ = (i >> 1) & 31, hw = (i & 1) << 3;
        half8 hv = *reinterpret_cast<half8*>(&vv[j]);
        half8 z = {(_Float16)0, (_Float16)0, (_Float16)0, (_Float16)0,
                   (_Float16)0, (_Float16)0, (_Float16)0, (_Float16)0};
        hv = sRst[b_] ? z : hv;
        *(half8*)&sA[b_ * LDK + p_ * 16 + hw] = hv;
      }
      __syncthreads(); // B: sA staged
    }

    run_gemm(sA, sWh, sGh, wid, lane);   // gh = h @ Wh_slice
    __syncthreads();                     // C

    // gates + publish
    {
      union { unsigned int u; _Float16 h[2]; } u0, u1, u2;
      u0.u = giu0; u1.u = giu1; u2.u = giu2;
#pragma unroll
      for (int e = 0; e < 2; ++e) {
        int cj = gcd * 2 + e;
        float gir = (float)u0.h[e];
        float giz = (float)u1.h[e];
        float gin = (float)u2.h[e];
        float ghr = sGh[gb * LDG + cj]      + sBh[cj];
        float ghz = sGh[gb * LDG + 16 + cj] + sBh[16 + cj];
        float ghn = sGh[gb * LDG + 32 + cj] + sBh[32 + cj];
        float r = 1.f / (1.f + __expf(-(gir + ghr)));
        float z = 1.f / (1.f + __expf(-(giz + ghz)));
        float n = tanhf(gin + r * ghn);
        float hp = sRst[gb] ? 0.f : hreg[e];
        hreg[e] = (1.f - z) * n + z * hp;
      }
      union { _Float16 h[2]; unsigned int u; } pk;
      pk.h[0] = (_Float16)hreg[0];
      pk.h[1] = (_Float16)hreg[1];
      unsigned int* dst = ex[t & 1] + p * 1024 + (row0 + gb) * 8 + gcd;
      asm volatile("global_store_dword %0, %1, off sc0 sc1"
                   :: "v"(dst), "v"(pk.u) : "memory");
    }
    asm volatile("s_waitcnt vmcnt(0)" ::: "memory");  // drain exchange store
    __syncthreads();                                  // D: all waves drained
    if (tid == 0) {
      unsigned int* fdst = flags + (size_t)bid * FLAG_STRIDE;
      unsigned int val = (unsigned)(t + 1);
      asm volatile("global_store_dword %0, %1, off sc0 sc1"
                   :: "v"(fdst), "v"(val) : "memory");
    }
    // ys store AFTER the flag: write-only data, off the critical path
    {
      float2 yv = make_float2(hreg[0], hreg[1]);
      *(float2*)&ys[((size_t)t * BATCH + row0 + gb) * HDIM + col0 + gcd * 2] = yv;
      if (t == T_STEPS - 1)
        *(float2*)&carryOut[(size_t)(row0 + gb) * HDIM + col0 + gcd * 2] = yv;
    }
  }
}

extern "C" void kernel_launch(void* const* d_in, const int* in_sizes, int n_in,
                              void* d_out, int out_size, void* d_ws, size_t ws_size,
                              hipStream_t stream) {
  const float* carry  = (const float*)d_in[0];
  const float* ins    = (const float*)d_in[1];
  const void*  resets = (const void*)d_in[2];
  const float* Wi     = (const float*)d_in[3];
  const float* Wh     = (const float*)d_in[4];
  const float* bh     = (const float*)d_in[5];
  float* out = (float*)d_out;

  unsigned int* flags = (unsigned int*)d_ws;                          // 2KB (also v1 cnt)
  unsigned int* dec   = (unsigned int*)((char*)d_ws + DEC_OFF);
  unsigned int* ex0   = (unsigned int*)((char*)d_ws + EX_OFF);
  unsigned int* ex1   = ex0 + EX_DWORDS;
  _Float16*     gis   = (_Float16*)((char*)d_ws + GI_OFF);

  (void)hipMemsetAsync(d_ws, 0, 4096, stream);

  sniff_kernel<<<dim3(1), dim3(THREADS), 0, stream>>>(
      (const unsigned int*)resets, dec);

  const bool bigWs = ws_size >= (size_t)GI_OFF + GI_BYTES;

  if (bigWs) {
    gi_prepass<<<dim3(512), dim3(256), 0, stream>>>(ins, Wi, gis);
    void* args[] = { (void*)&carry, (void*)&resets, (void*)&Wh, (void*)&bh,
                     (void*)&out, (void*)&flags, (void*)&ex0, (void*)&ex1,
                     (void*)&gis, (void*)&dec };
    (void)hipLaunchCooperativeKernel((const void*)gru_kernel_v3,
                                     dim3(NGROUP * NSLICE), dim3(THREADS),
                                     args, 0, stream);
  } else {
    void* args[] = { (void*)&carry, (void*)&ins, (void*)&resets, (void*)&Wi,
                     (void*)&Wh, (void*)&bh, (void*)&out, (void*)&flags,
                     (void*)&ex0, (void*)&ex1, (void*)&dec };
    (void)hipLaunchCooperativeKernel((const void*)gru_kernel_v1,
                                     dim3(NGROUP * NSLICE), dim3(THREADS),
                                     args, 0, stream);
  }
}

// Round 7
// 2328.902 us; speedup vs baseline: 4.3566x; 1.6425x over previous
//
#include <hip/hip_runtime.h>

#define T_STEPS 512
#define BATCH   128
#define DIN     512
#define HDIM    512
#define THREEH  1536
#define THREADS 256
#define LDK     520    // padded K stride in halves
#define LDG     49
#define NGROUP  4
#define NSLICE  32
#define BC      32
#define HC      16
#define NC      48
#define CNT_STRIDE 16
#define FLAG_STRIDE 4
#define SPIN_MAX (1 << 22)   // bounded spin: wedge -> wrong answer, not a hang
#define EX_DWORDS (NSLICE * BATCH * HC / 2)   // 32768 dwords = 128KB per slot
// ws layout
#define DEC_OFF    2048
#define EX_OFF     4096      // 2 x 128KB
#define GI_OFF     (1u<<20)
#define GI_BYTES   201326592ULL  // T*B*3H fp16

typedef _Float16 half8 __attribute__((ext_vector_type(8)));
typedef _Float16 half4v __attribute__((ext_vector_type(4)));
typedef float    f32x4 __attribute__((ext_vector_type(4)));
typedef unsigned int uint4v __attribute__((ext_vector_type(4)));

__global__ void sniff_kernel(const unsigned int* __restrict__ w,
                             unsigned int* __restrict__ dec) {
  unsigned int local = 0;
  for (int i = threadIdx.x; i < (T_STEPS * BATCH) / 4; i += THREADS) {
    if (w[i] > 1u) local = 1u;
  }
  if (local) atomicOr(dec, 1u);
}

__device__ __forceinline__ void run_gemm(const _Float16* __restrict__ sAa,
                                         const _Float16* __restrict__ sW,
                                         float* __restrict__ sAcc,
                                         int wid, int lane) {
  const int fr = lane & 15;
  const int kb = (lane >> 4) * 8;
  for (int tile = wid; tile < 6; tile += 4) {
    int mi = tile / 3, ni = tile - mi * 3;
    const _Float16* ap = sAa + (mi * 16 + fr) * LDK + kb;
    const _Float16* bp = sW  + (ni * 16 + fr) * LDK + kb;
    f32x4 acc = {0.f, 0.f, 0.f, 0.f};
#pragma unroll
    for (int kk = 0; kk < DIN / 32; ++kk)
      acc = __builtin_amdgcn_mfma_f32_16x16x32_f16(
          *(const half8*)(ap + kk * 32),
          *(const half8*)(bp + kk * 32), acc, 0, 0, 0);
    int crow = mi * 16 + (lane >> 4) * 4;
    int ccol = ni * 16 + fr;
#pragma unroll
    for (int j = 0; j < 4; ++j) sAcc[(crow + j) * LDG + ccol] = acc[j];
  }
}

// ======================= v1 fallback (round-4, proven) =======================
__global__ __launch_bounds__(THREADS, 1)
void gru_kernel_v1(const float* __restrict__ carry,
                   const float* __restrict__ ins,
                   const void*  __restrict__ resets_raw,
                   const float* __restrict__ Wi,
                   const float* __restrict__ Wh,
                   const float* __restrict__ bh,
                   float* __restrict__ out,
                   unsigned int* __restrict__ cnt,
                   unsigned int* __restrict__ ex0,
                   unsigned int* __restrict__ ex1,
                   const unsigned int* __restrict__ dec)
{
  __shared__ alignas(16) _Float16 sWi[NC * LDK];
  __shared__ alignas(16) _Float16 sWh[NC * LDK];
  __shared__ alignas(16) _Float16 sA [BC * LDK];
  __shared__ float sGi[BC * LDG];
  __shared__ float sGh[BC * LDG];
  __shared__ float sBh[NC];
  __shared__ int   sRst[BC];

  const int tid  = threadIdx.x;
  const int bid  = blockIdx.x;
  const int g    = bid & (NGROUP - 1);
  const int p    = bid >> 2;
  const int row0 = g * BC;
  const int col0 = p * HC;

  float* carryOut = out;
  float* ys = out + BATCH * HDIM;

  const unsigned int isBool = *dec;
  const unsigned char* r8  = (const unsigned char*)resets_raw;
  const int*           r32 = (const int*)resets_raw;

  unsigned int* ex[2] = { ex0, ex1 };
  unsigned int* myCnt = cnt + g * CNT_STRIDE;

  for (int idx = tid; idx < DIN * NC; idx += THREADS) {
    int k  = idx / NC;
    int ci = idx - k * NC;
    int gcol = (ci >> 4) * HDIM + col0 + (ci & 15);
    sWi[ci * LDK + k] = (_Float16)Wi[k * THREEH + gcol];
    sWh[ci * LDK + k] = (_Float16)Wh[k * THREEH + gcol];
  }
  if (tid < NC) {
    int gcol = (tid >> 4) * HDIM + col0 + (tid & 15);
    sBh[tid] = bh[gcol];
  }

  float hreg[2];
  {
    int idx = tid * 2;
    int b0 = idx >> 4, c0 = idx & 15;
    hreg[0] = carry[(size_t)(row0 + b0) * HDIM + col0 + c0];
    hreg[1] = carry[(size_t)(row0 + b0) * HDIM + col0 + c0 + 1];
  }

  const int wid  = tid >> 6;
  const int lane = tid & 63;

  auto stageRst = [&](int t) {
    if (tid < BC) {
      int off = t * BATCH + row0 + tid;
      sRst[tid] = isBool ? (int)r8[off] : r32[off];
    }
  };
  auto stageX = [&](int t) {
    const float4* src = (const float4*)(ins + (size_t)(t * BATCH + row0) * DIN);
    for (int i = tid; i < BC * (DIN / 4); i += THREADS) {
      int r = i >> 7, c4 = i & 127;
      float4 v = src[(size_t)r * 128 + c4];
      half4v hv = {(_Float16)v.x, (_Float16)v.y, (_Float16)v.z, (_Float16)v.w};
      *(half4v*)&sA[r * LDK + c4 * 4] = hv;
    }
  };

  stageRst(0);
  stageX(0);
  __syncthreads();
  run_gemm(sA, sWi, sGi, wid, lane);
  __syncthreads();
  {
    const float4* src = (const float4*)(carry + (size_t)row0 * HDIM);
    for (int i = tid; i < BC * (HDIM / 4); i += THREADS) {
      int r = i >> 7, c4 = i & 127;
      float4 v = src[(size_t)r * 128 + c4];
      float m = sRst[r] ? 0.f : 1.f;
      half4v hv = {(_Float16)(v.x*m), (_Float16)(v.y*m),
                   (_Float16)(v.z*m), (_Float16)(v.w*m)};
      *(half4v*)&sA[r * LDK + c4 * 4] = hv;
    }
  }
  __syncthreads();

  for (int t = 0; t < T_STEPS; ++t) {
    if (t > 0) {
      {
        const unsigned int target = 32u * (unsigned)t;
        unsigned int fv;
        for (int it = 0; it < SPIN_MAX; ++it) {
          asm volatile("global_load_dword %0, %1, off sc0 sc1\n\t"
                       "s_waitcnt vmcnt(0)"
                       : "=v"(fv) : "v"(myCnt) : "memory");
          if (fv >= target) break;
          __builtin_amdgcn_s_sleep(1);
        }
      }
      {
        const unsigned int* exsrc = ex[(t - 1) & 1];
        uint4v vv[8];
#pragma unroll
        for (int j = 0; j < 8; ++j) {
          int i = tid + THREADS * j;
          int p_ = i >> 6, b_ = (i >> 1) & 31, hw = (i & 1) << 2;
          const unsigned int* sp = exsrc + p_ * 1024 + (row0 + b_) * 8 + hw;
          asm volatile("global_load_dwordx4 %0, %1, off sc0 sc1"
                       : "=&v"(vv[j]) : "v"(sp) : "memory");
        }
        asm volatile("s_waitcnt vmcnt(0)" ::: "memory");
        __builtin_amdgcn_sched_barrier(0);
#pragma unroll
        for (int j = 0; j < 8; ++j) {
          int i = tid + THREADS * j;
          int p_ = i >> 6, b_ = (i >> 1) & 31, hw = (i & 1) << 3;
          half8 hv = *reinterpret_cast<half8*>(&vv[j]);
          half8 z = {(_Float16)0, (_Float16)0, (_Float16)0, (_Float16)0,
                     (_Float16)0, (_Float16)0, (_Float16)0, (_Float16)0};
          hv = sRst[b_] ? z : hv;
          *(half8*)&sA[b_ * LDK + p_ * 16 + hw] = hv;
        }
      }
      __syncthreads();
    }

    run_gemm(sA, sWh, sGh, wid, lane);
    __syncthreads();

    {
#pragma unroll
      for (int e = 0; e < 2; ++e) {
        int idx = tid * 2 + e;
        int b = idx >> 4, cj = idx & 15;
        float gir = sGi[b * LDG + cj];
        float giz = sGi[b * LDG + 16 + cj];
        float gin = sGi[b * LDG + 32 + cj];
        float ghr = sGh[b * LDG + cj]      + sBh[cj];
        float ghz = sGh[b * LDG + 16 + cj] + sBh[16 + cj];
        float ghn = sGh[b * LDG + 32 + cj] + sBh[32 + cj];
        float r = 1.f / (1.f + __expf(-(gir + ghr)));
        float z = 1.f / (1.f + __expf(-(giz + ghz)));
        float n = tanhf(gin + r * ghn);
        float hp = sRst[b] ? 0.f : hreg[e];
        hreg[e] = (1.f - z) * n + z * hp;
      }
      union { _Float16 h[2]; unsigned int u; } pk;
      pk.h[0] = (_Float16)hreg[0];
      pk.h[1] = (_Float16)hreg[1];
      unsigned int* dst = ex[t & 1] + p * 1024 + (row0 + (tid >> 3)) * 8 + (tid & 7);
      asm volatile("global_store_dword %0, %1, off sc0 sc1"
                   :: "v"(dst), "v"(pk.u) : "memory");
      int b0 = (tid * 2) >> 4, c0 = (tid * 2) & 15;
      float2 yv = make_float2(hreg[0], hreg[1]);
      *(float2*)&ys[((size_t)t * BATCH + row0 + b0) * HDIM + col0 + c0] = yv;
      if (t == T_STEPS - 1)
        *(float2*)&carryOut[(size_t)(row0 + b0) * HDIM + col0 + c0] = yv;
    }
    asm volatile("s_waitcnt vmcnt(0)" ::: "memory");
    __syncthreads();
    if (tid == 0) atomicAdd(myCnt, 1u);

    if (t < T_STEPS - 1) {
      stageRst(t + 1);
      stageX(t + 1);
      __syncthreads();
      run_gemm(sA, sWi, sGi, wid, lane);
      __syncthreads();
    }
  }
}

// ============ gi prepass v2: register-pipelined staging ============
// grid 256: n = bid>>3 (32 col-slices), mg = bid&7 (8 M-stripes, XCD-aligned
// so all 32 n-slices of a stripe share one XCD's L2 -> ins fetched once).
__global__ __launch_bounds__(256, 1)
void gi_prepass2(const float* __restrict__ ins,
                 const float* __restrict__ Wi,
                 _Float16* __restrict__ gis)
{
  __shared__ alignas(16) _Float16 sWiT[48 * LDK];
  __shared__ alignas(16) _Float16 sX[32 * LDK];

  const int tid = threadIdx.x;
  const int bid = blockIdx.x;
  const int n   = bid >> 3;    // col-slice (16 h-cols)
  const int mg  = bid & 7;     // M-stripe of 8192 rows
  const int wid = tid >> 6;
  const int lane = tid & 63;
  const int fr = lane & 15;
  const int kb = (lane >> 4) * 8;

  // B slice (one-time)
  for (int idx = tid; idx < 48 * DIN; idx += 256) {
    int ci = idx % 48, k = idx / 48;
    int gcol = (ci >> 4) * HDIM + n * 16 + (ci & 15);
    sWiT[ci * LDK + k] = (_Float16)Wi[(size_t)k * THREEH + gcol];
  }

  float4 va[16];
  auto LOADS = [&](int ch) {
    const float4* src = (const float4*)(ins + (size_t)(mg * 8192 + ch * 32) * DIN);
#pragma unroll
    for (int j = 0; j < 16; ++j) va[j] = src[tid + 256 * j];
  };
  auto WRITE = [&]() {
#pragma unroll
    for (int j = 0; j < 16; ++j) {
      int i = tid + 256 * j;
      int r = i >> 7, c4 = i & 127;
      float4 v = va[j];
      half4v hv = {(_Float16)v.x, (_Float16)v.y, (_Float16)v.z, (_Float16)v.w};
      *(half4v*)&sX[r * LDK + c4 * 4] = hv;
    }
  };

  LOADS(0);
  for (int ch = 0; ch < 256; ++ch) {
    WRITE();                 // waits vmcnt for va; sWiT also done before barrier
    __syncthreads();         // sX ready
    if (ch + 1 < 256) LOADS(ch + 1);   // issue next chunk; lands during MFMA

    const int m0 = mg * 8192 + ch * 32;
    const int tt = m0 >> 7;            // 32-row chunk never crosses a t boundary
    const int bb0 = m0 & 127;
    for (int tile = wid; tile < 6; tile += 4) {
      int mi = tile / 3, ni = tile - mi * 3;
      const _Float16* ap = sX   + (mi * 16 + fr) * LDK + kb;
      const _Float16* bp = sWiT + (ni * 16 + fr) * LDK + kb;
      f32x4 acc = {0.f, 0.f, 0.f, 0.f};
#pragma unroll
      for (int kk = 0; kk < DIN / 32; ++kk)
        acc = __builtin_amdgcn_mfma_f32_16x16x32_f16(
            *(const half8*)(ap + kk * 32),
            *(const half8*)(bp + kk * 32), acc, 0, 0, 0);
      int gr = mi * 16 + ((lane >> 4) << 2);
      int col = n * 16 + fr;
      size_t base = ((size_t)(tt * 3 + ni) * BATCH) * HDIM + col;
#pragma unroll
      for (int j = 0; j < 4; ++j)
        gis[base + (size_t)(bb0 + gr + j) * HDIM] = (_Float16)acc[j];
    }
    __syncthreads();         // sX consumed -> safe to overwrite next iter
  }
}

// ============ v3: slim recurrent loop (gi from prepass buffer) ============
__global__ __launch_bounds__(THREADS, 1)
void gru_kernel_v3(const float* __restrict__ carry,
                   const void*  __restrict__ resets_raw,
                   const float* __restrict__ Wh,
                   const float* __restrict__ bh,
                   float* __restrict__ out,
                   unsigned int* __restrict__ flags,
                   unsigned int* __restrict__ ex0,
                   unsigned int* __restrict__ ex1,
                   const _Float16* __restrict__ gis,
                   const unsigned int* __restrict__ dec)
{
  __shared__ alignas(16) _Float16 sWh[NC * LDK];
  __shared__ alignas(16) _Float16 sA [BC * LDK];
  __shared__ float sGh[BC * LDG];
  __shared__ float sBh[NC];
  __shared__ int   sRst[BC];

  const int tid  = threadIdx.x;
  const int bid  = blockIdx.x;
  const int g    = bid & (NGROUP - 1);
  const int p    = bid >> 2;
  const int row0 = g * BC;
  const int col0 = p * HC;

  float* carryOut = out;
  float* ys = out + BATCH * HDIM;

  const unsigned int isBool = *dec;
  const unsigned char* r8  = (const unsigned char*)resets_raw;
  const int*           r32 = (const int*)resets_raw;

  unsigned int* ex[2] = { ex0, ex1 };

  for (int idx = tid; idx < DIN * NC; idx += THREADS) {
    int k  = idx / NC;
    int ci = idx - k * NC;
    int gcol = (ci >> 4) * HDIM + col0 + (ci & 15);
    sWh[ci * LDK + k] = (_Float16)Wh[k * THREEH + gcol];
  }
  if (tid < NC) {
    int gcol = (tid >> 4) * HDIM + col0 + (tid & 15);
    sBh[tid] = bh[gcol];
  }

  float hreg[2];
  {
    int idx = tid * 2;
    int b0 = idx >> 4, c0 = idx & 15;
    hreg[0] = carry[(size_t)(row0 + b0) * HDIM + col0 + c0];
    hreg[1] = carry[(size_t)(row0 + b0) * HDIM + col0 + c0 + 1];
  }

  const int wid  = tid >> 6;
  const int lane = tid & 63;
  const int gb   = tid >> 3;
  const int gcd  = tid & 7;

  if (tid < BC) {
    int off = row0 + tid;
    sRst[tid] = isBool ? (int)r8[off] : r32[off];
  }
  __syncthreads();
  {
    const float4* src = (const float4*)(carry + (size_t)row0 * HDIM);
    for (int i = tid; i < BC * (HDIM / 4); i += THREADS) {
      int r = i >> 7, c4 = i & 127;
      float4 v = src[(size_t)r * 128 + c4];
      float m = sRst[r] ? 0.f : 1.f;
      half4v hv = {(_Float16)(v.x*m), (_Float16)(v.y*m),
                   (_Float16)(v.z*m), (_Float16)(v.w*m)};
      *(half4v*)&sA[r * LDK + c4 * 4] = hv;
    }
  }

  for (int t = 0; t < T_STEPS; ++t) {
    unsigned int giu0, giu1, giu2;
    {
      const unsigned int* gp = (const unsigned int*)gis
        + ((((size_t)(t * 3) * BATCH + row0 + gb) * HDIM + col0) >> 1) + gcd;
      const size_t gstride = (size_t)BATCH * HDIM / 2;
      giu0 = gp[0];
      giu1 = gp[gstride];
      giu2 = gp[2 * gstride];
    }
    if (t > 0 && tid < BC) {
      int off = t * BATCH + row0 + tid;
      sRst[tid] = isBool ? (int)r8[off] : r32[off];
    }
    if (t > 0 && tid < NSLICE) {
      const unsigned int* fp = flags + (size_t)(g + NGROUP * tid) * FLAG_STRIDE;
      unsigned int fv;
      for (int it = 0; it < SPIN_MAX; ++it) {
        asm volatile("global_load_dword %0, %1, off sc0 sc1\n\t"
                     "s_waitcnt vmcnt(0)"
                     : "=v"(fv) : "v"(fp) : "memory");
        if (fv >= (unsigned)t) break;
        __builtin_amdgcn_s_sleep(1);
      }
    }
    __syncthreads();

    if (t > 0) {
      const unsigned int* exsrc = ex[(t - 1) & 1];
      uint4v vv[8];
#pragma unroll
      for (int j = 0; j < 8; ++j) {
        int i = tid + THREADS * j;
        int p_ = i >> 6, b_ = (i >> 1) & 31, hw = (i & 1) << 2;
        const unsigned int* sp = exsrc + p_ * 1024 + (row0 + b_) * 8 + hw;
        asm volatile("global_load_dwordx4 %0, %1, off sc0 sc1"
                     : "=&v"(vv[j]) : "v"(sp) : "memory");
      }
      asm volatile("s_waitcnt vmcnt(0)" ::: "memory");
      __builtin_amdgcn_sched_barrier(0);
#pragma unroll
      for (int j = 0; j < 8; ++j) {
        int i = tid + THREADS * j;
        int p_ = i >> 6, b_ = (i >> 1) & 31, hw = (i & 1) << 3;
        half8 hv = *reinterpret_cast<half8*>(&vv[j]);
        half8 z = {(_Float16)0, (_Float16)0, (_Float16)0, (_Float16)0,
                   (_Float16)0, (_Float16)0, (_Float16)0, (_Float16)0};
        hv = sRst[b_] ? z : hv;
        *(half8*)&sA[b_ * LDK + p_ * 16 + hw] = hv;
      }
      __syncthreads();
    }

    run_gemm(sA, sWh, sGh, wid, lane);
    __syncthreads();

    {
      union { unsigned int u; _Float16 h[2]; } u0, u1, u2;
      u0.u = giu0; u1.u = giu1; u2.u = giu2;
#pragma unroll
      for (int e = 0; e < 2; ++e) {
        int cj = gcd * 2 + e;
        float gir = (float)u0.h[e];
        float giz = (float)u1.h[e];
        float gin = (float)u2.h[e];
        float ghr = sGh[gb * LDG + cj]      + sBh[cj];
        float ghz = sGh[gb * LDG + 16 + cj] + sBh[16 + cj];
        float ghn = sGh[gb * LDG + 32 + cj] + sBh[32 + cj];
        float r = 1.f / (1.f + __expf(-(gir + ghr)));
        float z = 1.f / (1.f + __expf(-(giz + ghz)));
        float n = tanhf(gin + r * ghn);
        float hp = sRst[gb] ? 0.f : hreg[e];
        hreg[e] = (1.f - z) * n + z * hp;
      }
      union { _Float16 h[2]; unsigned int u; } pk;
      pk.h[0] = (_Float16)hreg[0];
      pk.h[1] = (_Float16)hreg[1];
      unsigned int* dst = ex[t & 1] + p * 1024 + (row0 + gb) * 8 + gcd;
      asm volatile("global_store_dword %0, %1, off sc0 sc1"
                   :: "v"(dst), "v"(pk.u) : "memory");
    }
    asm volatile("s_waitcnt vmcnt(0)" ::: "memory");
    __syncthreads();
    if (tid == 0) {
      unsigned int* fdst = flags + (size_t)bid * FLAG_STRIDE;
      unsigned int val = (unsigned)(t + 1);
      asm volatile("global_store_dword %0, %1, off sc0 sc1"
                   :: "v"(fdst), "v"(val) : "memory");
    }
    {
      float2 yv = make_float2(hreg[0], hreg[1]);
      *(float2*)&ys[((size_t)t * BATCH + row0 + gb) * HDIM + col0 + gcd * 2] = yv;
      if (t == T_STEPS - 1)
        *(float2*)&carryOut[(size_t)(row0 + gb) * HDIM + col0 + gcd * 2] = yv;
    }
  }
}

extern "C" void kernel_launch(void* const* d_in, const int* in_sizes, int n_in,
                              void* d_out, int out_size, void* d_ws, size_t ws_size,
                              hipStream_t stream) {
  const float* carry  = (const float*)d_in[0];
  const float* ins    = (const float*)d_in[1];
  const void*  resets = (const void*)d_in[2];
  const float* Wi     = (const float*)d_in[3];
  const float* Wh     = (const float*)d_in[4];
  const float* bh     = (const float*)d_in[5];
  float* out = (float*)d_out;

  unsigned int* flags = (unsigned int*)d_ws;
  unsigned int* dec   = (unsigned int*)((char*)d_ws + DEC_OFF);
  unsigned int* ex0   = (unsigned int*)((char*)d_ws + EX_OFF);
  unsigned int* ex1   = ex0 + EX_DWORDS;
  _Float16*     gis   = (_Float16*)((char*)d_ws + GI_OFF);

  (void)hipMemsetAsync(d_ws, 0, 4096, stream);

  sniff_kernel<<<dim3(1), dim3(THREADS), 0, stream>>>(
      (const unsigned int*)resets, dec);

  const bool bigWs = ws_size >= (size_t)GI_OFF + GI_BYTES;

  if (bigWs) {
    gi_prepass2<<<dim3(256), dim3(256), 0, stream>>>(ins, Wi, gis);
    void* args[] = { (void*)&carry, (void*)&resets, (void*)&Wh, (void*)&bh,
                     (void*)&out, (void*)&flags, (void*)&ex0, (void*)&ex1,
                     (void*)&gis, (void*)&dec };
    (void)hipLaunchCooperativeKernel((const void*)gru_kernel_v3,
                                     dim3(NGROUP * NSLICE), dim3(THREADS),
                                     args, 0, stream);
  } else {
    void* args[] = { (void*)&carry, (void*)&ins, (void*)&resets, (void*)&Wi,
                     (void*)&Wh, (void*)&bh, (void*)&out, (void*)&flags,
                     (void*)&ex0, (void*)&ex1, (void*)&dec };
    (void)hipLaunchCooperativeKernel((const void*)gru_kernel_v1,
                                     dim3(NGROUP * NSLICE), dim3(THREADS),
                                     args, 0, stream);
  }
}

// Round 8
// 2139.819 us; speedup vs baseline: 4.7415x; 1.0884x over previous
//
#include <hip/hip_runtime.h>

#define T_STEPS 512
#define BATCH   128
#define DIN     512
#define HDIM    512
#define THREEH  1536
#define THREADS 256
#define LDK     520    // padded K stride in halves
#define LDG     49
// v1 fallback geometry
#define NGROUP  4
#define NSLICE  32
#define BC      32
#define HC      16
#define NC      48
#define CNT_STRIDE 16
#define SPIN_MAX (1 << 16)   // bounded spin: wedge -> wrong answer + finish, never hang
#define EX_DWORDS (NSLICE * BATCH * HC / 2)
// v4 geometry: 8 groups x 16 rows; 32 slices x 16 cols
#define NG4 8
#define RW4 16
#define NS4 32
#define EXSLOT 131072        // bytes per exchange slot (8g x 16r x 512c x 2B)
// ws layout (first 4KB memset to 0 each launch)
#define FLAGS_OFF  0         // v4: 256 uints (cohort g owns line g*128B); v1: cnt
#define GBAR_OFF   1088      // 8 counters x 64B apart
#define DEC_OFF    1280
#define VD_OFF     2048      // 256 uints verdicts
#define HS_OFF     3072      // 256 uints handshake patterns
#define EX_OFF     4096      // 2 x 128KB (v4) / 2 x 128KB (v1)
#define GI_OFF     (1u<<20)
#define GI_BYTES   201326592ULL

typedef _Float16 half8 __attribute__((ext_vector_type(8)));
typedef _Float16 half4v __attribute__((ext_vector_type(4)));
typedef float    f32x4 __attribute__((ext_vector_type(4)));
typedef unsigned int uint4v __attribute__((ext_vector_type(4)));

__global__ void sniff_kernel(const unsigned int* __restrict__ w,
                             unsigned int* __restrict__ dec) {
  unsigned int local = 0;
  for (int i = threadIdx.x; i < (T_STEPS * BATCH) / 4; i += THREADS) {
    if (w[i] > 1u) local = 1u;
  }
  if (local) atomicOr(dec, 1u);
}

__device__ __forceinline__ void run_gemm(const _Float16* __restrict__ sAa,
                                         const _Float16* __restrict__ sW,
                                         float* __restrict__ sAcc,
                                         int wid, int lane) {
  const int fr = lane & 15;
  const int kb = (lane >> 4) * 8;
  for (int tile = wid; tile < 6; tile += 4) {
    int mi = tile / 3, ni = tile - mi * 3;
    const _Float16* ap = sAa + (mi * 16 + fr) * LDK + kb;
    const _Float16* bp = sW  + (ni * 16 + fr) * LDK + kb;
    f32x4 acc = {0.f, 0.f, 0.f, 0.f};
#pragma unroll
    for (int kk = 0; kk < DIN / 32; ++kk)
      acc = __builtin_amdgcn_mfma_f32_16x16x32_f16(
          *(const half8*)(ap + kk * 32),
          *(const half8*)(bp + kk * 32), acc, 0, 0, 0);
    int crow = mi * 16 + (lane >> 4) * 4;
    int ccol = ni * 16 + fr;
#pragma unroll
    for (int j = 0; j < 4; ++j) sAcc[(crow + j) * LDG + ccol] = acc[j];
  }
}

// ======================= v1 fallback (round-4, proven; small-ws only) =======================
__global__ __launch_bounds__(THREADS, 1)
void gru_kernel_v1(const float* __restrict__ carry,
                   const float* __restrict__ ins,
                   const void*  __restrict__ resets_raw,
                   const float* __restrict__ Wi,
                   const float* __restrict__ Wh,
                   const float* __restrict__ bh,
                   float* __restrict__ out,
                   unsigned int* __restrict__ cnt,
                   unsigned int* __restrict__ ex0,
                   unsigned int* __restrict__ ex1,
                   const unsigned int* __restrict__ dec)
{
  __shared__ alignas(16) _Float16 sWi[NC * LDK];
  __shared__ alignas(16) _Float16 sWh[NC * LDK];
  __shared__ alignas(16) _Float16 sA [BC * LDK];
  __shared__ float sGi[BC * LDG];
  __shared__ float sGh[BC * LDG];
  __shared__ float sBh[NC];
  __shared__ int   sRst[BC];

  const int tid  = threadIdx.x;
  const int bid  = blockIdx.x;
  const int g    = bid & (NGROUP - 1);
  const int p    = bid >> 2;
  const int row0 = g * BC;
  const int col0 = p * HC;

  float* carryOut = out;
  float* ys = out + BATCH * HDIM;

  const unsigned int isBool = *dec;
  const unsigned char* r8  = (const unsigned char*)resets_raw;
  const int*           r32 = (const int*)resets_raw;

  unsigned int* ex[2] = { ex0, ex1 };
  unsigned int* myCnt = cnt + g * CNT_STRIDE;

  for (int idx = tid; idx < DIN * NC; idx += THREADS) {
    int k  = idx / NC;
    int ci = idx - k * NC;
    int gcol = (ci >> 4) * HDIM + col0 + (ci & 15);
    sWi[ci * LDK + k] = (_Float16)Wi[k * THREEH + gcol];
    sWh[ci * LDK + k] = (_Float16)Wh[k * THREEH + gcol];
  }
  if (tid < NC) {
    int gcol = (tid >> 4) * HDIM + col0 + (tid & 15);
    sBh[tid] = bh[gcol];
  }

  float hreg[2];
  {
    int idx = tid * 2;
    int b0 = idx >> 4, c0 = idx & 15;
    hreg[0] = carry[(size_t)(row0 + b0) * HDIM + col0 + c0];
    hreg[1] = carry[(size_t)(row0 + b0) * HDIM + col0 + c0 + 1];
  }

  const int wid  = tid >> 6;
  const int lane = tid & 63;

  auto stageRst = [&](int t) {
    if (tid < BC) {
      int off = t * BATCH + row0 + tid;
      sRst[tid] = isBool ? (int)r8[off] : r32[off];
    }
  };
  auto stageX = [&](int t) {
    const float4* src = (const float4*)(ins + (size_t)(t * BATCH + row0) * DIN);
    for (int i = tid; i < BC * (DIN / 4); i += THREADS) {
      int r = i >> 7, c4 = i & 127;
      float4 v = src[(size_t)r * 128 + c4];
      half4v hv = {(_Float16)v.x, (_Float16)v.y, (_Float16)v.z, (_Float16)v.w};
      *(half4v*)&sA[r * LDK + c4 * 4] = hv;
    }
  };

  stageRst(0);
  stageX(0);
  __syncthreads();
  run_gemm(sA, sWi, sGi, wid, lane);
  __syncthreads();
  {
    const float4* src = (const float4*)(carry + (size_t)row0 * HDIM);
    for (int i = tid; i < BC * (HDIM / 4); i += THREADS) {
      int r = i >> 7, c4 = i & 127;
      float4 v = src[(size_t)r * 128 + c4];
      float m = sRst[r] ? 0.f : 1.f;
      half4v hv = {(_Float16)(v.x*m), (_Float16)(v.y*m),
                   (_Float16)(v.z*m), (_Float16)(v.w*m)};
      *(half4v*)&sA[r * LDK + c4 * 4] = hv;
    }
  }
  __syncthreads();

  for (int t = 0; t < T_STEPS; ++t) {
    if (t > 0) {
      {
        const unsigned int target = 32u * (unsigned)t;
        unsigned int fv;
        for (int it = 0; it < SPIN_MAX; ++it) {
          asm volatile("global_load_dword %0, %1, off sc0 sc1\n\t"
                       "s_waitcnt vmcnt(0)"
                       : "=v"(fv) : "v"(myCnt) : "memory");
          if (fv >= target) break;
          __builtin_amdgcn_s_sleep(1);
        }
      }
      {
        const unsigned int* exsrc = ex[(t - 1) & 1];
        uint4v vv[8];
#pragma unroll
        for (int j = 0; j < 8; ++j) {
          int i = tid + THREADS * j;
          int p_ = i >> 6, b_ = (i >> 1) & 31, hw = (i & 1) << 2;
          const unsigned int* sp = exsrc + p_ * 1024 + (row0 + b_) * 8 + hw;
          asm volatile("global_load_dwordx4 %0, %1, off sc0 sc1"
                       : "=&v"(vv[j]) : "v"(sp) : "memory");
        }
        asm volatile("s_waitcnt vmcnt(0)" ::: "memory");
        __builtin_amdgcn_sched_barrier(0);
#pragma unroll
        for (int j = 0; j < 8; ++j) {
          int i = tid + THREADS * j;
          int p_ = i >> 6, b_ = (i >> 1) & 31, hw = (i & 1) << 3;
          half8 hv = *reinterpret_cast<half8*>(&vv[j]);
          half8 z = {(_Float16)0, (_Float16)0, (_Float16)0, (_Float16)0,
                     (_Float16)0, (_Float16)0, (_Float16)0, (_Float16)0};
          hv = sRst[b_] ? z : hv;
          *(half8*)&sA[b_ * LDK + p_ * 16 + hw] = hv;
        }
      }
      __syncthreads();
    }

    run_gemm(sA, sWh, sGh, wid, lane);
    __syncthreads();

    {
#pragma unroll
      for (int e = 0; e < 2; ++e) {
        int idx = tid * 2 + e;
        int b = idx >> 4, cj = idx & 15;
        float gir = sGi[b * LDG + cj];
        float giz = sGi[b * LDG + 16 + cj];
        float gin = sGi[b * LDG + 32 + cj];
        float ghr = sGh[b * LDG + cj]      + sBh[cj];
        float ghz = sGh[b * LDG + 16 + cj] + sBh[16 + cj];
        float ghn = sGh[b * LDG + 32 + cj] + sBh[32 + cj];
        float r = 1.f / (1.f + __expf(-(gir + ghr)));
        float z = 1.f / (1.f + __expf(-(giz + ghz)));
        float n = tanhf(gin + r * ghn);
        float hp = sRst[b] ? 0.f : hreg[e];
        hreg[e] = (1.f - z) * n + z * hp;
      }
      union { _Float16 h[2]; unsigned int u; } pk;
      pk.h[0] = (_Float16)hreg[0];
      pk.h[1] = (_Float16)hreg[1];
      unsigned int* dst = ex[t & 1] + p * 1024 + (row0 + (tid >> 3)) * 8 + (tid & 7);
      asm volatile("global_store_dword %0, %1, off sc0 sc1"
                   :: "v"(dst), "v"(pk.u) : "memory");
      int b0 = (tid * 2) >> 4, c0 = (tid * 2) & 15;
      float2 yv = make_float2(hreg[0], hreg[1]);
      *(float2*)&ys[((size_t)t * BATCH + row0 + b0) * HDIM + col0 + c0] = yv;
      if (t == T_STEPS - 1)
        *(float2*)&carryOut[(size_t)(row0 + b0) * HDIM + col0 + c0] = yv;
    }
    asm volatile("s_waitcnt vmcnt(0)" ::: "memory");
    __syncthreads();
    if (tid == 0) atomicAdd(myCnt, 1u);

    if (t < T_STEPS - 1) {
      stageRst(t + 1);
      stageX(t + 1);
      __syncthreads();
      run_gemm(sA, sWi, sGi, wid, lane);
      __syncthreads();
    }
  }
}

// ============ gi prepass (round-7, proven): register-pipelined staging ============
__global__ __launch_bounds__(256, 1)
void gi_prepass2(const float* __restrict__ ins,
                 const float* __restrict__ Wi,
                 _Float16* __restrict__ gis)
{
  __shared__ alignas(16) _Float16 sWiT[48 * LDK];
  __shared__ alignas(16) _Float16 sX[32 * LDK];

  const int tid = threadIdx.x;
  const int bid = blockIdx.x;
  const int n   = bid >> 3;
  const int mg  = bid & 7;
  const int wid = tid >> 6;
  const int lane = tid & 63;
  const int fr = lane & 15;
  const int kb = (lane >> 4) * 8;

  for (int idx = tid; idx < 48 * DIN; idx += 256) {
    int ci = idx % 48, k = idx / 48;
    int gcol = (ci >> 4) * HDIM + n * 16 + (ci & 15);
    sWiT[ci * LDK + k] = (_Float16)Wi[(size_t)k * THREEH + gcol];
  }

  float4 va[16];
  auto LOADS = [&](int ch) {
    const float4* src = (const float4*)(ins + (size_t)(mg * 8192 + ch * 32) * DIN);
#pragma unroll
    for (int j = 0; j < 16; ++j) va[j] = src[tid + 256 * j];
  };
  auto WRITE = [&]() {
#pragma unroll
    for (int j = 0; j < 16; ++j) {
      int i = tid + 256 * j;
      int r = i >> 7, c4 = i & 127;
      float4 v = va[j];
      half4v hv = {(_Float16)v.x, (_Float16)v.y, (_Float16)v.z, (_Float16)v.w};
      *(half4v*)&sX[r * LDK + c4 * 4] = hv;
    }
  };

  LOADS(0);
  for (int ch = 0; ch < 256; ++ch) {
    WRITE();
    __syncthreads();
    if (ch + 1 < 256) LOADS(ch + 1);

    const int m0 = mg * 8192 + ch * 32;
    const int tt = m0 >> 7;
    const int bb0 = m0 & 127;
    for (int tile = wid; tile < 6; tile += 4) {
      int mi = tile / 3, ni = tile - mi * 3;
      const _Float16* ap = sX   + (mi * 16 + fr) * LDK + kb;
      const _Float16* bp = sWiT + (ni * 16 + fr) * LDK + kb;
      f32x4 acc = {0.f, 0.f, 0.f, 0.f};
#pragma unroll
      for (int kk = 0; kk < DIN / 32; ++kk)
        acc = __builtin_amdgcn_mfma_f32_16x16x32_f16(
            *(const half8*)(ap + kk * 32),
            *(const half8*)(bp + kk * 32), acc, 0, 0, 0);
      int gr = mi * 16 + ((lane >> 4) << 2);
      int col = n * 16 + fr;
      size_t base = ((size_t)(tt * 3 + ni) * BATCH) * HDIM + col;
#pragma unroll
      for (int j = 0; j < 4; ++j)
        gis[base + (size_t)(bb0 + gr + j) * HDIM] = (_Float16)acc[j];
    }
    __syncthreads();
  }
}

// ============ v4: XCD-local exchange with runtime visibility handshake ============
__device__ __forceinline__ void gridbar(unsigned int* ctr, int tid) {
  __syncthreads();
  if (tid == 0) {
    atomicAdd(ctr, 1u);
    unsigned int v;
    for (int it = 0; it < SPIN_MAX; ++it) {
      asm volatile("global_load_dword %0, %1, off sc0 sc1\n\t"
                   "s_waitcnt vmcnt(0)" : "=v"(v) : "v"(ctr) : "memory");
      if (v >= 256u) break;
      __builtin_amdgcn_s_sleep(1);
    }
  }
  __syncthreads();
}

__global__ __launch_bounds__(256, 1)
void gru_kernel_v4(const float* __restrict__ carry,
                   const void*  __restrict__ resets_raw,
                   const float* __restrict__ Wh,
                   const float* __restrict__ bh,
                   float* __restrict__ out,
                   unsigned int* __restrict__ wsb,
                   const _Float16* __restrict__ gis,
                   const unsigned int* __restrict__ dec)
{
  __shared__ alignas(16) _Float16 sWh[NC * LDK];   // ~50KB
  __shared__ alignas(16) _Float16 sA [RW4 * LDK];  // ~16.6KB
  __shared__ float sGh[RW4 * LDG];
  __shared__ float sBh[NC];
  __shared__ int   sRst[RW4];
  __shared__ int   sFast;

  const int tid  = threadIdx.x;
  const int bid  = blockIdx.x;
  const int g    = bid & 7;        // cohort (presumed XCD via round-robin)
  const int p    = bid >> 3;       // col slice 0..31
  const int row0 = g * RW4;
  const int col0 = p * HC;

  unsigned int* flags = wsb + (FLAGS_OFF / 4) ;    // cohort g owns flags[g*32..+31] = one 128B line
  unsigned int* gbars = wsb + (GBAR_OFF / 4);
  unsigned int* vd    = wsb + (VD_OFF / 4);
  unsigned int* hs    = wsb + (HS_OFF / 4);
  char*         exb   = (char*)wsb + EX_OFF;

  float* carryOut = out;
  float* ys = out + BATCH * HDIM;

  const unsigned int isBool = *dec;
  const unsigned char* r8  = (const unsigned char*)resets_raw;
  const int*           r32 = (const int*)resets_raw;

  // ---------------- handshake: is my cohort co-resident on one L2? ----------------
  bool ok1 = true, ok2 = true;
  {
    unsigned int PAT1 = 0xC0DE0000u | (unsigned)bid;
    unsigned int PAT2 = 0xFACE0000u | (unsigned)bid;
    if (tid == 0) {
      unsigned int* hp = hs + bid;
      asm volatile("global_store_dword %0, %1, off sc0\n\t"
                   "s_waitcnt vmcnt(0)" :: "v"(hp), "v"(PAT1) : "memory");
    }
    gridbar(gbars + 0 * 16, tid);
    if (tid < 32) {
      int peer = g + 8 * tid;
      unsigned int v;
      const unsigned int* hp = hs + peer;
      asm volatile("global_load_dword %0, %1, off sc0\n\t"
                   "s_waitcnt vmcnt(0)" : "=v"(v) : "v"(hp) : "memory");
      ok1 = (v == (0xC0DE0000u | (unsigned)peer));
    }
    gridbar(gbars + 1 * 16, tid);
    if (tid == 0) {
      unsigned int* hp = hs + bid;
      asm volatile("global_store_dword %0, %1, off sc0\n\t"
                   "s_waitcnt vmcnt(0)" :: "v"(hp), "v"(PAT2) : "memory");
    }
    gridbar(gbars + 2 * 16, tid);
    if (tid < 32) {
      int peer = g + 8 * tid;
      unsigned int v;
      const unsigned int* hp = hs + peer;
      asm volatile("global_load_dword %0, %1, off sc0\n\t"
                   "s_waitcnt vmcnt(0)" : "=v"(v) : "v"(hp) : "memory");
      ok2 = (v == (0xFACE0000u | (unsigned)peer));
    }
    // wave0 aggregates; publish WG verdict via MALL
    bool myok = (tid < 32) ? (ok1 && ok2) : true;
    bool wgok = __all(myok);    // valid in wave0
    if (tid == 0) {
      unsigned int vv = wgok ? 1u : 0u;
      unsigned int* vp = vd + bid;
      asm volatile("global_store_dword %0, %1, off sc0 sc1\n\t"
                   "s_waitcnt vmcnt(0)" :: "v"(vp), "v"(vv) : "memory");
    }
    gridbar(gbars + 3 * 16, tid);
    bool fin = true;
    if (tid < 32) {
      int peer = g + 8 * tid;
      unsigned int v;
      const unsigned int* vp = vd + peer;
      asm volatile("global_load_dword %0, %1, off sc0 sc1\n\t"
                   "s_waitcnt vmcnt(0)" : "=v"(v) : "v"(vp) : "memory");
      fin = (v == 1u);
    }
    bool unan = __all((tid < 32) ? fin : true);
    if (tid == 0) sFast = unan ? 1 : 0;
    __syncthreads();
  }
  const int fast = sFast;

  // zero my flag slot in the domain we'll use, then grid barrier
  if (tid == 0) {
    unsigned int* fp = flags + (g * 32 + p);
    unsigned int zz = 0u;
    if (fast) {
      asm volatile("global_store_dword %0, %1, off sc0\n\t"
                   "s_waitcnt vmcnt(0)" :: "v"(fp), "v"(zz) : "memory");
    } else {
      asm volatile("global_store_dword %0, %1, off sc0 sc1\n\t"
                   "s_waitcnt vmcnt(0)" :: "v"(fp), "v"(zz) : "memory");
    }
  }
  gridbar(gbars + 4 * 16, tid);

  // ---------------- weights / bias / state init ----------------
  for (int idx = tid; idx < DIN * NC; idx += THREADS) {
    int k  = idx / NC;
    int ci = idx - k * NC;
    int gcol = (ci >> 4) * HDIM + col0 + (ci & 15);
    sWh[ci * LDK + k] = (_Float16)Wh[k * THREEH + gcol];
  }
  if (tid < NC) {
    int gcol = (tid >> 4) * HDIM + col0 + (tid & 15);
    sBh[tid] = bh[gcol];
  }

  const int gb = tid >> 4;       // batch row 0..15
  const int gc = tid & 15;       // col within slice 0..15
  float hreg = carry[(size_t)(row0 + gb) * HDIM + col0 + gc];

  const int wid  = tid >> 6;
  const int lane = tid & 63;
  const int fr   = lane & 15;
  const int kb   = (lane >> 4) * 8;

  // prologue: rst(0) + stage masked carry into sA
  if (tid < RW4) {
    int off = row0 + tid;
    sRst[tid] = isBool ? (int)r8[off] : r32[off];
  }
  __syncthreads();
  {
    const float4* src = (const float4*)(carry + (size_t)row0 * HDIM);
    for (int i = tid; i < RW4 * (HDIM / 4); i += THREADS) {
      int r = i >> 7, c4 = i & 127;
      float4 v = src[(size_t)r * 128 + c4];
      float m = sRst[r] ? 0.f : 1.f;
      half4v hv = {(_Float16)(v.x*m), (_Float16)(v.y*m),
                   (_Float16)(v.z*m), (_Float16)(v.w*m)};
      *(half4v*)&sA[r * LDK + c4 * 4] = hv;
    }
  }

  const unsigned short* gisu = (const unsigned short*)gis;

  for (int t = 0; t < T_STEPS; ++t) {
    // gi loads (plain cached; recurrence-independent)
    unsigned short gu0, gu1, gu2;
    {
      size_t base = ((size_t)(t * 3) * BATCH + row0 + gb) * HDIM + col0 + gc;
      gu0 = gisu[base];
      gu1 = gisu[base + (size_t)BATCH * HDIM];
      gu2 = gisu[base + 2 * (size_t)BATCH * HDIM];
    }
    if (t > 0 && tid < RW4) {
      int off = t * BATCH + row0 + tid;
      sRst[tid] = isBool ? (int)r8[off] : r32[off];
    }
    // wait for cohort flags (wave0 lanes 0..31 poll one 128B line)
    if (t > 0) {
      bool done = false;
      const unsigned int* fp = flags + (g * 32 + (tid & 31));
      for (int it = 0; it < SPIN_MAX && !done; ++it) {
        unsigned int fv = 0xFFFFFFFFu;
        if (tid < 32) {
          if (fast) {
            asm volatile("global_load_dword %0, %1, off sc0\n\t"
                         "s_waitcnt vmcnt(0)" : "=v"(fv) : "v"(fp) : "memory");
          } else {
            asm volatile("global_load_dword %0, %1, off sc0 sc1\n\t"
                         "s_waitcnt vmcnt(0)" : "=v"(fv) : "v"(fp) : "memory");
          }
        }
        done = __all((tid < 32) ? (fv >= (unsigned)t) : true);
        if (!done) __builtin_amdgcn_s_sleep(1);
      }
    }
    __syncthreads();

    if (t > 0) {
      // stage h_{t-1}: 16KB from cohort-local region
      const char* src = exb + ((t - 1) & 1) * EXSLOT + g * 16384
                      + (tid >> 4) * 1024 + (tid & 15) * 64;
      uint4v v0, v1, v2, v3;
      if (fast) {
        asm volatile("global_load_dwordx4 %0, %4, off sc0\n\t"
                     "global_load_dwordx4 %1, %4, off offset:16 sc0\n\t"
                     "global_load_dwordx4 %2, %4, off offset:32 sc0\n\t"
                     "global_load_dwordx4 %3, %4, off offset:48 sc0\n\t"
                     "s_waitcnt vmcnt(0)"
                     : "=&v"(v0), "=&v"(v1), "=&v"(v2), "=&v"(v3)
                     : "v"(src) : "memory");
      } else {
        asm volatile("global_load_dwordx4 %0, %4, off sc0 sc1\n\t"
                     "global_load_dwordx4 %1, %4, off offset:16 sc0 sc1\n\t"
                     "global_load_dwordx4 %2, %4, off offset:32 sc0 sc1\n\t"
                     "global_load_dwordx4 %3, %4, off offset:48 sc0 sc1\n\t"
                     "s_waitcnt vmcnt(0)"
                     : "=&v"(v0), "=&v"(v1), "=&v"(v2), "=&v"(v3)
                     : "v"(src) : "memory");
      }
      __builtin_amdgcn_sched_barrier(0);
      int r = tid >> 4, c0 = (tid & 15) * 32;
      half8 h0 = *reinterpret_cast<half8*>(&v0);
      half8 h1 = *reinterpret_cast<half8*>(&v1);
      half8 h2 = *reinterpret_cast<half8*>(&v2);
      half8 h3 = *reinterpret_cast<half8*>(&v3);
      half8 z = {(_Float16)0, (_Float16)0, (_Float16)0, (_Float16)0,
                 (_Float16)0, (_Float16)0, (_Float16)0, (_Float16)0};
      if (sRst[r]) { h0 = z; h1 = z; h2 = z; h3 = z; }
      *(half8*)&sA[r * LDK + c0 +  0] = h0;
      *(half8*)&sA[r * LDK + c0 +  8] = h1;
      *(half8*)&sA[r * LDK + c0 + 16] = h2;
      *(half8*)&sA[r * LDK + c0 + 24] = h3;
      __syncthreads();
    }

    // gemm: M=16, 3 ni-tiles over waves 0..2 (split-K acc pair)
    if (wid < 3) {
      const int ni = wid;
      const _Float16* ap = sA  + fr * LDK + kb;
      const _Float16* bp = sWh + (ni * 16 + fr) * LDK + kb;
      f32x4 a0 = {0.f, 0.f, 0.f, 0.f}, a1 = {0.f, 0.f, 0.f, 0.f};
#pragma unroll
      for (int kk = 0; kk < DIN / 32; kk += 2) {
        a0 = __builtin_amdgcn_mfma_f32_16x16x32_f16(
            *(const half8*)(ap + kk * 32), *(const half8*)(bp + kk * 32), a0, 0, 0, 0);
        a1 = __builtin_amdgcn_mfma_f32_16x16x32_f16(
            *(const half8*)(ap + (kk + 1) * 32), *(const half8*)(bp + (kk + 1) * 32), a1, 0, 0, 0);
      }
      a0 += a1;
      int crow = (lane >> 4) * 4;
      int ccol = ni * 16 + fr;
#pragma unroll
      for (int j = 0; j < 4; ++j) sGh[(crow + j) * LDG + ccol] = a0[j];
    }
    __syncthreads();

    // gates (1 elem/thread) + publish
    {
      union { unsigned short u; _Float16 h; } c0_, c1_, c2_;
      c0_.u = gu0; c1_.u = gu1; c2_.u = gu2;
      float gir = (float)c0_.h;
      float giz = (float)c1_.h;
      float gin = (float)c2_.h;
      float ghr = sGh[gb * LDG + gc]      + sBh[gc];
      float ghz = sGh[gb * LDG + 16 + gc] + sBh[16 + gc];
      float ghn = sGh[gb * LDG + 32 + gc] + sBh[32 + gc];
      float r = 1.f / (1.f + __expf(-(gir + ghr)));
      float z = 1.f / (1.f + __expf(-(giz + ghz)));
      float n = tanhf(gin + r * ghn);
      float hp = sRst[gb] ? 0.f : hreg;
      hreg = (1.f - z) * n + z * hp;

      union { _Float16 h; unsigned short u; } pk;
      pk.h = (_Float16)hreg;
      unsigned int pv = (unsigned int)pk.u;
      unsigned short* dst = (unsigned short*)
        (exb + (t & 1) * EXSLOT + g * 16384 + gb * 1024 + (col0 + gc) * 2);
      if (fast) {
        asm volatile("global_store_short %0, %1, off sc0"
                     :: "v"(dst), "v"(pv) : "memory");
      } else {
        asm volatile("global_store_short %0, %1, off sc0 sc1"
                     :: "v"(dst), "v"(pv) : "memory");
      }
    }
    asm volatile("s_waitcnt vmcnt(0)" ::: "memory");
    __syncthreads();
    if (tid == 0) {
      unsigned int* fp = flags + (g * 32 + p);
      unsigned int val = (unsigned)(t + 1);
      if (fast) {
        asm volatile("global_store_dword %0, %1, off sc0"
                     :: "v"(fp), "v"(val) : "memory");
      } else {
        asm volatile("global_store_dword %0, %1, off sc0 sc1"
                     :: "v"(fp), "v"(val) : "memory");
      }
    }
    // ys (write-only) after the flag, off the critical path
    {
      ys[((size_t)t * BATCH + row0 + gb) * HDIM + col0 + gc] = hreg;
      if (t == T_STEPS - 1)
        carryOut[(size_t)(row0 + gb) * HDIM + col0 + gc] = hreg;
    }
  }

  // flush dirty L2 lines so no stale data can leak into a later replay
  __builtin_amdgcn_fence(__ATOMIC_RELEASE, "agent");
}

extern "C" void kernel_launch(void* const* d_in, const int* in_sizes, int n_in,
                              void* d_out, int out_size, void* d_ws, size_t ws_size,
                              hipStream_t stream) {
  const float* carry  = (const float*)d_in[0];
  const float* ins    = (const float*)d_in[1];
  const void*  resets = (const void*)d_in[2];
  const float* Wi     = (const float*)d_in[3];
  const float* Wh     = (const float*)d_in[4];
  const float* bh     = (const float*)d_in[5];
  float* out = (float*)d_out;

  unsigned int* wsb  = (unsigned int*)d_ws;
  unsigned int* dec  = (unsigned int*)((char*)d_ws + DEC_OFF);
  unsigned int* ex0  = (unsigned int*)((char*)d_ws + EX_OFF);
  unsigned int* ex1  = ex0 + EX_DWORDS;
  _Float16*     gis  = (_Float16*)((char*)d_ws + GI_OFF);

  (void)hipMemsetAsync(d_ws, 0, 4096, stream);

  sniff_kernel<<<dim3(1), dim3(THREADS), 0, stream>>>(
      (const unsigned int*)resets, dec);

  const bool bigWs = ws_size >= (size_t)GI_OFF + GI_BYTES;

  if (bigWs) {
    gi_prepass2<<<dim3(256), dim3(256), 0, stream>>>(ins, Wi, gis);
    void* args[] = { (void*)&carry, (void*)&resets, (void*)&Wh, (void*)&bh,
                     (void*)&out, (void*)&wsb, (void*)&gis, (void*)&dec };
    (void)hipLaunchCooperativeKernel((const void*)gru_kernel_v4,
                                     dim3(256), dim3(256),
                                     args, 0, stream);
  } else {
    void* args[] = { (void*)&carry, (void*)&ins, (void*)&resets, (void*)&Wi,
                     (void*)&Wh, (void*)&bh, (void*)&out, (void*)&wsb,
                     (void*)&ex0, (void*)&ex1, (void*)&dec };
    (void)hipLaunchCooperativeKernel((const void*)gru_kernel_v1,
                                     dim3(NGROUP * NSLICE), dim3(THREADS),
                                     args, 0, stream);
  }
}